// Round 5
// baseline (396.868 us; speedup 1.0000x reference)
//
#include <hip/hip_runtime.h>
#include <hip/hip_bf16.h>
#include <cstdint>
#include <cstddef>

#define DI __device__ __forceinline__

// ---------- constants ----------
#define NN 500
#define NQ 2000           // B*N
#define GTOT 32768        // G*TOTAL
#define LN_EPS 1e-5f

typedef __attribute__((ext_vector_type(8))) short short8v;
typedef __attribute__((ext_vector_type(4))) float f32x4;
typedef const __attribute__((address_space(1))) void* gp1_t;
typedef __attribute__((address_space(3))) void* lp3_t;

DI unsigned short f2bf(float f){
  unsigned u = __float_as_uint(f);
  return (unsigned short)((u + 0x7fffu + ((u>>16)&1u)) >> 16);
}
DI float bf2f(unsigned short s){ return __uint_as_float(((unsigned)s)<<16); }

// block-wide (256 thr = 4 waves) sum of s, s2
DI void bred256(float& s, float& s2, float* red, int tid){
  #pragma unroll
  for(int off=32; off; off>>=1){
    s  += __shfl_xor(s,  off, 64);
    s2 += __shfl_xor(s2, off, 64);
  }
  int w = tid>>6;
  if((tid&63)==0){ red[w*2]=s; red[w*2+1]=s2; }
  __syncthreads();
  s  = red[0]+red[2]+red[4]+red[6];
  s2 = red[1]+red[3]+red[5]+red[7];
  __syncthreads();
}

// ---------- K0: feature transpose (B,C,H,W) f32 -> (B*G,H,W,64) bf16 ----------
__global__ __launch_bounds__(256) void k_transpose(const float* __restrict__ src,
    unsigned short* __restrict__ dst, int H, int W){
  __shared__ float tile[64][161];
  int bg = blockIdx.x / H, h = blockIdx.x % H;
  int b = bg >> 2, g = bg & 3;
  const float* s = src + (((size_t)(b*256 + g*64))*H + h)*(size_t)W;
  for(int idx=threadIdx.x; idx<64*W; idx+=256){
    int c = idx / W, w = idx - c*W;
    tile[c][w] = s[(size_t)c*H*W + w];
  }
  __syncthreads();
  unsigned short* d = dst + ((size_t)bg*H + h)*(size_t)W*64;
  for(int idx=threadIdx.x; idx<64*W; idx+=256){
    int w = idx>>6, c = idx&63;
    d[idx] = f2bf(tile[c][w]);
  }
}

// ---------- K1: offset GEMM + sample coords + level softmax ----------
__global__ __launch_bounds__(384) void k_off(const float* __restrict__ qf,
    const float* __restrict__ xyzr, const float* __restrict__ w_off,
    const float* __restrict__ b_off, float2* __restrict__ xyb, float4* __restrict__ lwb){
  __shared__ float qs[8][256];
  __shared__ float os[8][384];
  int q0 = blockIdx.x*8, tid = threadIdx.x;
  for(int idx=tid; idx<2048; idx+=384){
    int qq = idx>>8, k = idx&255;
    qs[qq][k] = qf[(size_t)(q0+qq)*256 + k];
  }
  __syncthreads();
  {
    int j = tid;
    float acc[8];
    #pragma unroll
    for(int i=0;i<8;i++) acc[i]=0.f;
    for(int k=0;k<256;k++){
      float w = w_off[(size_t)k*384 + j];
      #pragma unroll
      for(int qq=0;qq<8;qq++) acc[qq] += qs[qq][k]*w;
    }
    float bb = b_off[j];
    #pragma unroll
    for(int qq=0;qq<8;qq++) os[qq][j] = acc[qq] + bb;
  }
  __syncthreads();
  for(int idx=tid; idx<1024; idx+=384){
    int qq = idx>>7, gp = idx&127;
    int q = q0+qq;
    float4 xr = *(const float4*)&xyzr[(size_t)q*4];
    float rw = exp2f(xr.z - 0.5f*xr.w);
    float rh = exp2f(xr.z + 0.5f*xr.w);
    float sx = xr.x + os[qq][gp*3+0]*rw;
    float sy = xr.y + os[qq][gp*3+1]*rh;
    float lvl = xr.z + os[qq][gp*3+2] - 3.0f;
    float d0=lvl, d1=lvl-1.f, d2=lvl-2.f, d3=lvl-3.f;
    float e0=-0.5f*d0*d0, e1=-0.5f*d1*d1, e2=-0.5f*d2*d2, e3=-0.5f*d3*d3;
    float m = fmaxf(fmaxf(e0,e1),fmaxf(e2,e3));
    float x0=expf(e0-m), x1=expf(e1-m), x2=expf(e2-m), x3=expf(e3-m);
    float inv = 1.f/(x0+x1+x2+x3);
    xyb[(size_t)q*128+gp] = make_float2(sx,sy);
    lwb[(size_t)q*128+gp] = make_float4(x0*inv, x1*inv, x2*inv, x3*inv);
  }
}

// ---------- K-cvt: qf f32[2000][256] -> bf16[2048][256], pad rows zeroed ----------
__global__ __launch_bounds__(256) void k_cvtqf(const float* __restrict__ qf,
    unsigned short* __restrict__ qfb){
  int idx = blockIdx.x*256 + threadIdx.x;   // one per 8 elems; 65536 total
  size_t base = (size_t)idx*8;
  int row = idx >> 5;
  ushort4 lo, hi;
  if(row < NQ){
    float4 a = *(const float4*)(qf + base);
    float4 b = *(const float4*)(qf + base + 4);
    lo.x=f2bf(a.x); lo.y=f2bf(a.y); lo.z=f2bf(a.z); lo.w=f2bf(a.w);
    hi.x=f2bf(b.x); hi.y=f2bf(b.y); hi.z=f2bf(b.z); hi.w=f2bf(b.w);
  } else {
    lo.x=lo.y=lo.z=lo.w=0; hi.x=hi.y=hi.z=hi.w=0;
  }
  *(ushort4*)(qfb + base) = lo;
  *(ushort4*)(qfb + base + 4) = hi;
}

// ---------- K-trcvt: src f32 [R][C] -> dst bf16 [C][R] (R,C multiples of 64) ----------
__global__ __launch_bounds__(256) void k_trcvt(const float* __restrict__ src,
    unsigned short* __restrict__ dst, int R, int C){
  __shared__ float tile[64][65];
  int ctiles = C >> 6;
  int rt = blockIdx.x / ctiles, ct = blockIdx.x % ctiles;
  int r0 = rt<<6, c0 = ct<<6;
  int tid = threadIdx.x;
  int lr = tid>>6, lc = tid&63;
  #pragma unroll
  for(int i=0;i<16;i++)
    tile[lr + i*4][lc] = src[(size_t)(r0+lr+i*4)*C + c0+lc];
  __syncthreads();
  #pragma unroll
  for(int i=0;i<16;i++)
    dst[(size_t)(c0+lr+i*4)*R + r0+lc] = f2bf(tile[lc][lr+i*4]);
}

// ---------- MFMA helpers ----------
DI f32x4 mfma16(short8v a, short8v b, f32x4 c){
  return __builtin_amdgcn_mfma_f32_16x16x32_bf16(a, b, c, 0, 0, 0);
}

// stage a 128x64 bf16 tile into linear LDS via global_load_lds, source pre-swizzled
// so that read-side XOR (chunk ^ (row&7)) lands on the right data.
DI void stageG(const unsigned short* __restrict__ g, size_t row0, size_t ldk,
               size_t k0, unsigned short* lds, int tid){
  int wv = tid>>6;
  #pragma unroll
  for(int i=0;i<4;i++){
    int e = i*256 + tid;          // 16B-chunk index 0..1023
    int r = e>>3, c = e&7;
    int cs = c ^ (r&7);
    const unsigned short* gp = g + (row0 + (size_t)r)*ldk + k0 + (size_t)cs*8;
    unsigned short* lp = lds + (size_t)(i*256 + wv*64)*8;   // wave-uniform base
    __builtin_amdgcn_global_load_lds((gp1_t)(const void*)gp, (lp3_t)(void*)lp, 16, 0, 0);
  }
}

// read one A/B fragment from swizzled [128][64] tile
DI short8v frag(const unsigned short* lds, int row, int chunk){
  int byte = (row<<7) + (((chunk ^ (row&7)))<<4);
  return *(const short8v*)((const char*)lds + byte);
}

// 128x128 tile, one BK=64 buffer: 4 waves in 2x2 grid, acc[4][4]
DI void mma64(const unsigned short* lsA, const unsigned short* lsB,
              int wm, int wn, int lane, f32x4 acc[4][4]){
  int r15 = lane&15, q4 = lane>>4;
  #pragma unroll
  for(int ks=0; ks<2; ks++){
    short8v a[4], b[4];
    #pragma unroll
    for(int i=0;i<4;i++){
      a[i] = frag(lsA, wm*64 + i*16 + r15, ks*4 + q4);
      b[i] = frag(lsB, wn*64 + i*16 + r15, ks*4 + q4);
    }
    #pragma unroll
    for(int mi=0;mi<4;mi++)
      #pragma unroll
      for(int ni=0;ni<4;ni++)
        acc[mi][ni] = mfma16(a[mi], b[ni], acc[mi][ni]);
  }
}

// XCD-affinity remap: consecutive logical blocks land on one XCD (nwg % 8 == 0).
DI int xcd_remap(int bid, int nwg){
  return ((bid & 7) * (nwg >> 3)) + (bid >> 3);
}

// ---------- K2: params GEMM via MFMA: par = qfb @ wpgT^T + b_pg ----------
__global__ __launch_bounds__(256, 2) void k_pgemm_mfma(const unsigned short* __restrict__ qfb,
    const unsigned short* __restrict__ wpgT, const float* __restrict__ b_pg,
    unsigned short* __restrict__ par, int qbase, int qlim, int mtiles){
  __shared__ unsigned short lsA[2][128*64], lsB[2][128*64];
  int bid = xcd_remap(blockIdx.x, gridDim.x);
  int mt = bid % mtiles, nt = bid / mtiles;
  size_t m0 = (size_t)mt*128, n0 = (size_t)nt*128;
  int tid = threadIdx.x, lane = tid&63, wv = tid>>6;
  int wm = wv>>1, wn = wv&1;
  f32x4 acc[4][4] = {};
  stageG(qfb,  qbase+m0, 256, 0, lsA[0], tid);
  stageG(wpgT, n0,       256, 0, lsB[0], tid);
  __syncthreads();
  #pragma unroll
  for(int kb=0; kb<4; kb++){
    int cur = kb&1;
    if(kb<3){
      stageG(qfb,  qbase+m0, 256, (size_t)(kb+1)*64, lsA[cur^1], tid);
      stageG(wpgT, n0,       256, (size_t)(kb+1)*64, lsB[cur^1], tid);
    }
    mma64(lsA[cur], lsB[cur], wm, wn, lane, acc);
    __syncthreads();
  }
  int r15 = lane&15, q4 = lane>>4;
  #pragma unroll
  for(int ni=0; ni<4; ni++){
    int col = (int)n0 + wn*64 + ni*16 + r15;
    float bias = b_pg[col];
    #pragma unroll
    for(int mi=0; mi<4; mi++){
      #pragma unroll
      for(int j=0; j<4; j++){
        int rl = (int)m0 + wm*64 + mi*16 + q4*4 + j;
        if(qbase + rl < qlim)
          par[(size_t)rl*GTOT + col] = f2bf(acc[mi][ni][j] + bias);
      }
    }
  }
}

// ---------- K4: final GEMM via MFMA, K-split x16 -> f32 partials ----------
__global__ __launch_bounds__(256, 2) void k_fgemm_mfma(const unsigned short* __restrict__ A,
    const unsigned short* __restrict__ woutT, float* __restrict__ part,
    int qbase, int qlim, int mtiles){
  __shared__ unsigned short lsA[2][128*64], lsB[2][128*64];
  int bid = xcd_remap(blockIdx.x, gridDim.x);
  int mt = bid % mtiles;
  int r2 = bid / mtiles;
  int nt = r2 & 1, ks = r2 >> 1;
  size_t m0 = (size_t)mt*128, n0 = (size_t)nt*128;
  int tid = threadIdx.x, lane = tid&63, wv = tid>>6;
  int wm = wv>>1, wn = wv&1;
  f32x4 acc[4][4] = {};
  size_t kbase = (size_t)ks*2048;
  stageG(A,     m0, GTOT, kbase, lsA[0], tid);
  stageG(woutT, n0, GTOT, kbase, lsB[0], tid);
  __syncthreads();
  for(int kb=0; kb<32; kb++){
    int cur = kb&1;
    if(kb<31){
      stageG(A,     m0, GTOT, kbase + (size_t)(kb+1)*64, lsA[cur^1], tid);
      stageG(woutT, n0, GTOT, kbase + (size_t)(kb+1)*64, lsB[cur^1], tid);
    }
    mma64(lsA[cur], lsB[cur], wm, wn, lane, acc);
    __syncthreads();
  }
  float* pp = part + (size_t)ks*NQ*256;
  int r15 = lane&15, q4 = lane>>4;
  #pragma unroll
  for(int mi=0; mi<4; mi++){
    #pragma unroll
    for(int j=0; j<4; j++){
      int rl = (int)m0 + wm*64 + mi*16 + q4*4 + j;
      int q = qbase + rl;
      if(q < qlim){
        #pragma unroll
        for(int ni=0; ni<4; ni++){
          int col = (int)n0 + wn*64 + ni*16 + r15;
          pp[(size_t)q*256 + col] = acc[mi][ni][j];
        }
      }
    }
  }
}

// ---------- K3: sampling + M/S mixing via MFMA + two group-LN+relu -> out2 bf16 ----------
// NOTE: out2 may alias par — each block reads its full par slice into registers
// before any out2 store (same (lq,g) range, disjoint across blocks).
__global__ __launch_bounds__(256) void k_mix(const unsigned short* __restrict__ featT,
    const float2* __restrict__ xyb, const float4* __restrict__ lwb,
    const unsigned short* __restrict__ par, unsigned short* __restrict__ out2,
    int qbase){
  __shared__ __align__(16) char poolA[23040];
  __shared__ __align__(16) unsigned short Ss[128*40];   // S natural [o][p], pad 40
  __shared__ float red[8];
  float* offW = (float*)poolA;
  unsigned short* xs  = (unsigned short*)(poolA + 4096);
  unsigned short* Ms  = (unsigned short*)(poolA + 4096 + 4608);
  unsigned short* o1t = (unsigned short*)(poolA + 4096 + 4608 + 9216);
  unsigned short* o2s = (unsigned short*)poolA;

  int lq = blockIdx.x >> 2, g = blockIdx.x & 3;
  int q = qbase + lq;
  int b = q / NN;
  int bg = b*4 + g;
  int tid = threadIdx.x;
  int lane = tid & 63, wv = tid >> 6;

  const int HH[4] = {100,50,25,13};
  const int WW[4] = {160,80,40,20};
  const float IS[4] = {0.125f, 0.0625f, 0.03125f, 0.015625f};
  const int LO[4] = {0, 16384000, 20480000, 21504000};

  const unsigned short* pb = par + (size_t)lq*GTOT + (size_t)g*8192;
  uint4 mraw0 = *(const uint4*)(pb + tid*8);
  uint4 mraw1 = *(const uint4*)(pb + 2048 + tid*8);
  uint4 sraw0 = *(const uint4*)(pb + 4096 + tid*8);
  uint4 sraw1 = *(const uint4*)(pb + 6144 + tid*8);

  if(tid < 128){
    int p = tid >> 2, l = tid & 3;
    int pi = q*128 + g*32 + p;
    float2 xy = xyb[pi];
    float lw4 = ((const float*)lwb)[(size_t)pi*4 + l];
    int H = HH[l], W = WW[l];
    float px = xy.x*IS[l] - 0.5f;
    float py = xy.y*IS[l] - 0.5f;
    float xf = floorf(px), yf = floorf(py);
    float wx = px - xf, wy = py - yf;
    int x0 = (int)xf, y0 = (int)yf;
    int x1 = x0 + 1, y1 = y0 + 1;
    bool vx0 = (x0>=0)&&(x0<W), vx1 = (x1>=0)&&(x1<W);
    bool vy0 = (y0>=0)&&(y0<H), vy1 = (y1>=0)&&(y1<H);
    int x0c = min(max(x0,0),W-1), x1c = min(max(x1,0),W-1);
    int y0c = min(max(y0,0),H-1), y1c = min(max(y1,0),H-1);
    int base = LO[l] + bg*H*W*64;
    float* e = offW + tid*8;
    e[0] = __int_as_float(base + (y0c*W + x0c)*64);
    e[1] = __int_as_float(base + (y0c*W + x1c)*64);
    e[2] = __int_as_float(base + (y1c*W + x0c)*64);
    e[3] = __int_as_float(base + (y1c*W + x1c)*64);
    e[4] = (1.f-wx)*(1.f-wy)*lw4*(float)(vx0&&vy0);
    e[5] = wx*(1.f-wy)*lw4*(float)(vx1&&vy0);
    e[6] = (1.f-wx)*wy*lw4*(float)(vx0&&vy1);
    e[7] = wx*wy*lw4*(float)(vx1&&vy1);
  }

  {
    int idx0 = tid*8;
    int c0 = idx0>>6, d0 = idx0&63;
    *(uint4*)(Ms + c0*72 + d0) = mraw0;
    int idx1 = 2048 + tid*8;
    int c1 = idx1>>6, d1 = idx1&63;
    *(uint4*)(Ms + c1*72 + d1) = mraw1;
    int o0 = idx0>>5, p0 = idx0&31;
    *(uint4*)(Ss + o0*40 + p0) = sraw0;
    int o1_ = idx1>>5, p1 = idx1&31;
    *(uint4*)(Ss + o1_*40 + p1) = sraw1;
  }
  __syncthreads();

  #pragma unroll
  for(int i=0;i<8;i++){
    int p = wv*8 + i;
    const float* e = offW + p*32;
    float acc = 0.f;
    #pragma unroll
    for(int l=0;l<4;l++){
      const float* el = e + l*8;
      int o00 = __float_as_int(el[0]), o01 = __float_as_int(el[1]);
      int o10 = __float_as_int(el[2]), o11 = __float_as_int(el[3]);
      acc += el[4]*bf2f(featT[o00 + lane]);
      acc += el[5]*bf2f(featT[o01 + lane]);
      acc += el[6]*bf2f(featT[o10 + lane]);
      acc += el[7]*bf2f(featT[o11 + lane]);
    }
    xs[p*72 + lane] = f2bf(acc);
  }
  __syncthreads();

  int r = lane & 15, q4 = lane >> 4;

  // Phase B: out1 = x(32x64) @ M(64x64)
  {
    short8v af00 = *(const short8v*)(xs + r*72 + q4*8);
    short8v af01 = *(const short8v*)(xs + r*72 + 32 + q4*8);
    short8v af10 = *(const short8v*)(xs + (16+r)*72 + q4*8);
    short8v af11 = *(const short8v*)(xs + (16+r)*72 + 32 + q4*8);
    short8v bm0, bm1;
    #pragma unroll
    for(int j=0;j<8;j++){
      bm0[j] = (short)Ms[(8*q4+j)*72 + wv*16 + r];
      bm1[j] = (short)Ms[(32+8*q4+j)*72 + wv*16 + r];
    }
    f32x4 a0 = {}, a1 = {};
    a0 = mfma16(af00, bm0, a0); a0 = mfma16(af01, bm1, a0);
    a1 = mfma16(af10, bm0, a1); a1 = mfma16(af11, bm1, a1);

    float s = 0.f, s2 = 0.f;
    #pragma unroll
    for(int v=0;v<4;v++){ s += a0[v]+a1[v]; s2 += a0[v]*a0[v] + a1[v]*a1[v]; }
    bred256(s, s2, red, tid);
    float mean = s*(1.f/2048.f);
    float var = s2*(1.f/2048.f) - mean*mean;
    float rs = rsqrtf(var + LN_EPS);
    #pragma unroll
    for(int v=0;v<4;v++){
      float f0 = (a0[v]-mean)*rs; f0 = f0>0.f ? f0 : 0.f;
      float f1 = (a1[v]-mean)*rs; f1 = f1>0.f ? f1 : 0.f;
      o1t[(wv*16+r)*40 + 4*q4 + v] = f2bf(f0);
      o1t[(wv*16+r)*40 + 16 + 4*q4 + v] = f2bf(f1);
    }
  }
  __syncthreads();

  // Phase C: out2 = S(128x32) @ out1(32x64)
  {
    short8v sa0 = *(const short8v*)(Ss + ((wv*2+0)*16 + r)*40 + q4*8);
    short8v sa1 = *(const short8v*)(Ss + ((wv*2+1)*16 + r)*40 + q4*8);
    short8v ov0 = *(const short8v*)(o1t + (r)*40 + q4*8);
    short8v ov1 = *(const short8v*)(o1t + (16+r)*40 + q4*8);
    short8v ov2 = *(const short8v*)(o1t + (32+r)*40 + q4*8);
    short8v ov3 = *(const short8v*)(o1t + (48+r)*40 + q4*8);
    f32x4 c2[2][4] = {};
    c2[0][0] = mfma16(sa0, ov0, c2[0][0]); c2[0][1] = mfma16(sa0, ov1, c2[0][1]);
    c2[0][2] = mfma16(sa0, ov2, c2[0][2]); c2[0][3] = mfma16(sa0, ov3, c2[0][3]);
    c2[1][0] = mfma16(sa1, ov0, c2[1][0]); c2[1][1] = mfma16(sa1, ov1, c2[1][1]);
    c2[1][2] = mfma16(sa1, ov2, c2[1][2]); c2[1][3] = mfma16(sa1, ov3, c2[1][3]);

    float s = 0.f, s2 = 0.f;
    #pragma unroll
    for(int m=0;m<2;m++)
      #pragma unroll
      for(int ni=0;ni<4;ni++)
        #pragma unroll
        for(int v=0;v<4;v++){ float x = c2[m][ni][v]; s += x; s2 += x*x; }
    bred256(s, s2, red, tid);
    float mean = s*(1.f/8192.f);
    float var = s2*(1.f/8192.f) - mean*mean;
    float rs = rsqrtf(var + LN_EPS);
    #pragma unroll
    for(int m=0;m<2;m++)
      #pragma unroll
      for(int ni=0;ni<4;ni++)
        #pragma unroll
        for(int v=0;v<4;v++){
          float x = (c2[m][ni][v]-mean)*rs; x = x>0.f ? x : 0.f;
          int o = (wv*2+m)*16 + 4*q4 + v;
          int d = ni*16 + r;
          o2s[o*72 + d] = f2bf(x);
        }
  }
  __syncthreads();

  unsigned short* og = out2 + (size_t)lq*GTOT + (size_t)g*8192;
  #pragma unroll
  for(int i=0;i<32;i++){
    int row = wv*32 + i;
    og[row*64 + lane] = o2s[row*72 + lane];
  }
}

// ---------- K5: K-split reduce + bias + residual + LayerNorm ----------
__global__ __launch_bounds__(256) void k_ln(const float* __restrict__ part,
    const float* __restrict__ qf, const float* __restrict__ b_out,
    const float* __restrict__ ln_g, const float* __restrict__ ln_b,
    float* __restrict__ out){
  __shared__ float red[8];
  int q = blockIdx.x, j = threadIdx.x;
  float s = qf[(size_t)q*256 + j] + b_out[j];
  #pragma unroll
  for(int ks=0; ks<16; ks++) s += part[((size_t)ks*NQ + q)*256 + j];
  float a = s, a2 = s*s;
  bred256(a, a2, red, j);
  float mean = a*(1.f/256.f);
  float var = a2*(1.f/256.f) - mean*mean;
  float rs = rsqrtf(var + LN_EPS);
  out[(size_t)q*256 + j] = (s-mean)*rs*ln_g[j] + ln_b[j];
}

// ---------- launch ----------
extern "C" void kernel_launch(void* const* d_in, const int* in_sizes, int n_in,
                              void* d_out, int out_size, void* d_ws, size_t ws_size,
                              hipStream_t stream) {
  const float* feat0 = (const float*)d_in[0];
  const float* feat1 = (const float*)d_in[1];
  const float* feat2 = (const float*)d_in[2];
  const float* feat3 = (const float*)d_in[3];
  const float* qf    = (const float*)d_in[4];
  const float* xyzr  = (const float*)d_in[5];
  const float* w_off = (const float*)d_in[6];
  const float* b_off = (const float*)d_in[7];
  const float* w_pg  = (const float*)d_in[8];
  const float* b_pg  = (const float*)d_in[9];
  const float* w_out = (const float*)d_in[10];
  const float* b_out = (const float*)d_in[11];
  const float* ln_g  = (const float*)d_in[12];
  const float* ln_b  = (const float*)d_in[13];

  size_t off = 0;
  auto alloc = [&](size_t bytes){ size_t r = off; off = (off + bytes + 255) & ~255ull; return r; };
  size_t oFEAT = alloc(43540480ull);              // featT bf16
  size_t oXY   = alloc((size_t)NQ*128*8);         // float2
  size_t oLW   = alloc((size_t)NQ*128*16);        // float4
  size_t oPART = alloc((size_t)16*NQ*256*4);      // f32 partials
  size_t oQFB  = alloc((size_t)2048*256*2);       // qf bf16 padded
  size_t oWPGT = alloc((size_t)GTOT*256*2);       // w_pg^T bf16
  size_t oWOUT = alloc((size_t)256*GTOT*2);       // w_out^T bf16
  size_t fixedEnd = off;

  // out2 aliases par (each k_mix block fully reads its par slice before storing),
  // so only ONE chunk buffer is needed.
  int NC = 0; int qcount = 0, qpad = 0;
  for (int t = 1; t <= 8; t *= 2) {
    int qc = NQ / t;
    int qp = (qc + 127) & ~127;
    size_t c = (((size_t)qp*GTOT*2) + 255) & ~255ull;
    if (fixedEnd + c <= ws_size) { NC = t; qcount = qc; qpad = qp; break; }
  }
  if (NC == 0) return;
  size_t oPAR = fixedEnd;

  char* ws = (char*)d_ws;
  unsigned short* featT = (unsigned short*)(ws + oFEAT);
  float2* xyb = (float2*)(ws + oXY);
  float4* lwb = (float4*)(ws + oLW);
  float* part = (float*)(ws + oPART);
  unsigned short* qfb  = (unsigned short*)(ws + oQFB);
  unsigned short* wpgT = (unsigned short*)(ws + oWPGT);
  unsigned short* woutT= (unsigned short*)(ws + oWOUT);
  unsigned short* par  = (unsigned short*)(ws + oPAR);
  unsigned short* o2   = par;   // aliased

  k_transpose<<<16*100, 256, 0, stream>>>(feat0, featT + 0ull,        100, 160);
  k_transpose<<<16*50,  256, 0, stream>>>(feat1, featT + 16384000ull,  50,  80);
  k_transpose<<<16*25,  256, 0, stream>>>(feat2, featT + 20480000ull,  25,  40);
  k_transpose<<<16*13,  256, 0, stream>>>(feat3, featT + 21504000ull,  13,  20);
  k_off<<<250, 384, 0, stream>>>(qf, xyzr, w_off, b_off, xyb, lwb);
  k_cvtqf<<<256, 256, 0, stream>>>(qf, qfb);
  k_trcvt<<<2048, 256, 0, stream>>>(w_pg,  wpgT, 256, GTOT);   // [256][32768] -> [32768][256]
  k_trcvt<<<2048, 256, 0, stream>>>(w_out, woutT, GTOT, 256);  // [32768][256] -> [256][32768]

  int mtiles = qpad / 128;
  for (int c = 0; c < NC; ++c) {
    int qbase = c * qcount;
    int qlim  = qbase + qcount;
    k_pgemm_mfma<<<mtiles*256, 256, 0, stream>>>(qfb, wpgT, b_pg, par, qbase, qlim, mtiles);
    k_mix<<<qcount*4, 256, 0, stream>>>(featT, xyb, lwb, par, o2, qbase);
    k_fgemm_mfma<<<mtiles*32, 256, 0, stream>>>(o2, woutT, part, qbase, qlim, mtiles);
  }
  k_ln<<<NQ, 256, 0, stream>>>(part, qf, b_out, ln_g, ln_b, (float*)d_out);
}

// Round 6
// 386.180 us; speedup vs baseline: 1.0277x; 1.0277x over previous
//
#include <hip/hip_runtime.h>
#include <hip/hip_bf16.h>
#include <cstdint>
#include <cstddef>

#define DI __device__ __forceinline__

// ---------- constants ----------
#define NN 500
#define NQ 2000           // B*N
#define GTOT 32768        // G*TOTAL
#define LN_EPS 1e-5f

typedef __attribute__((ext_vector_type(8))) short short8v;
typedef __attribute__((ext_vector_type(4))) float f32x4;
typedef const __attribute__((address_space(1))) void* gp1_t;
typedef __attribute__((address_space(3))) void* lp3_t;

DI unsigned short f2bf(float f){
  unsigned u = __float_as_uint(f);
  return (unsigned short)((u + 0x7fffu + ((u>>16)&1u)) >> 16);
}
DI float bf2f(unsigned short s){ return __uint_as_float(((unsigned)s)<<16); }

// block-wide (256 thr = 4 waves) sum of s, s2
DI void bred256(float& s, float& s2, float* red, int tid){
  #pragma unroll
  for(int off=32; off; off>>=1){
    s  += __shfl_xor(s,  off, 64);
    s2 += __shfl_xor(s2, off, 64);
  }
  int w = tid>>6;
  if((tid&63)==0){ red[w*2]=s; red[w*2+1]=s2; }
  __syncthreads();
  s  = red[0]+red[2]+red[4]+red[6];
  s2 = red[1]+red[3]+red[5]+red[7];
  __syncthreads();
}

// ---------- K0: feature transpose (B,C,H,W) f32 -> (B*G,H,W,64) bf16 ----------
__global__ __launch_bounds__(256) void k_transpose(const float* __restrict__ src,
    unsigned short* __restrict__ dst, int H, int W){
  __shared__ float tile[64][161];
  int bg = blockIdx.x / H, h = blockIdx.x % H;
  int b = bg >> 2, g = bg & 3;
  const float* s = src + (((size_t)(b*256 + g*64))*H + h)*(size_t)W;
  for(int idx=threadIdx.x; idx<64*W; idx+=256){
    int c = idx / W, w = idx - c*W;
    tile[c][w] = s[(size_t)c*H*W + w];
  }
  __syncthreads();
  unsigned short* d = dst + ((size_t)bg*H + h)*(size_t)W*64;
  for(int idx=threadIdx.x; idx<64*W; idx+=256){
    int w = idx>>6, c = idx&63;
    d[idx] = f2bf(tile[c][w]);
  }
}

// ---------- K1: offset GEMM + sample coords + level softmax ----------
__global__ __launch_bounds__(384) void k_off(const float* __restrict__ qf,
    const float* __restrict__ xyzr, const float* __restrict__ w_off,
    const float* __restrict__ b_off, float2* __restrict__ xyb, float4* __restrict__ lwb){
  __shared__ float qs[8][256];
  __shared__ float os[8][384];
  int q0 = blockIdx.x*8, tid = threadIdx.x;
  for(int idx=tid; idx<2048; idx+=384){
    int qq = idx>>8, k = idx&255;
    qs[qq][k] = qf[(size_t)(q0+qq)*256 + k];
  }
  __syncthreads();
  {
    int j = tid;
    float acc[8];
    #pragma unroll
    for(int i=0;i<8;i++) acc[i]=0.f;
    for(int k=0;k<256;k++){
      float w = w_off[(size_t)k*384 + j];
      #pragma unroll
      for(int qq=0;qq<8;qq++) acc[qq] += qs[qq][k]*w;
    }
    float bb = b_off[j];
    #pragma unroll
    for(int qq=0;qq<8;qq++) os[qq][j] = acc[qq] + bb;
  }
  __syncthreads();
  for(int idx=tid; idx<1024; idx+=384){
    int qq = idx>>7, gp = idx&127;
    int q = q0+qq;
    float4 xr = *(const float4*)&xyzr[(size_t)q*4];
    float rw = exp2f(xr.z - 0.5f*xr.w);
    float rh = exp2f(xr.z + 0.5f*xr.w);
    float sx = xr.x + os[qq][gp*3+0]*rw;
    float sy = xr.y + os[qq][gp*3+1]*rh;
    float lvl = xr.z + os[qq][gp*3+2] - 3.0f;
    float d0=lvl, d1=lvl-1.f, d2=lvl-2.f, d3=lvl-3.f;
    float e0=-0.5f*d0*d0, e1=-0.5f*d1*d1, e2=-0.5f*d2*d2, e3=-0.5f*d3*d3;
    float m = fmaxf(fmaxf(e0,e1),fmaxf(e2,e3));
    float x0=expf(e0-m), x1=expf(e1-m), x2=expf(e2-m), x3=expf(e3-m);
    float inv = 1.f/(x0+x1+x2+x3);
    xyb[(size_t)q*128+gp] = make_float2(sx,sy);
    lwb[(size_t)q*128+gp] = make_float4(x0*inv, x1*inv, x2*inv, x3*inv);
  }
}

// ---------- K-cvt: qf f32[2000][256] -> bf16[2048][256], pad rows zeroed ----------
__global__ __launch_bounds__(256) void k_cvtqf(const float* __restrict__ qf,
    unsigned short* __restrict__ qfb){
  int idx = blockIdx.x*256 + threadIdx.x;   // one per 8 elems; 65536 total
  size_t base = (size_t)idx*8;
  int row = idx >> 5;
  ushort4 lo, hi;
  if(row < NQ){
    float4 a = *(const float4*)(qf + base);
    float4 b = *(const float4*)(qf + base + 4);
    lo.x=f2bf(a.x); lo.y=f2bf(a.y); lo.z=f2bf(a.z); lo.w=f2bf(a.w);
    hi.x=f2bf(b.x); hi.y=f2bf(b.y); hi.z=f2bf(b.z); hi.w=f2bf(b.w);
  } else {
    lo.x=lo.y=lo.z=lo.w=0; hi.x=hi.y=hi.z=hi.w=0;
  }
  *(ushort4*)(qfb + base) = lo;
  *(ushort4*)(qfb + base + 4) = hi;
}

// ---------- K-trcvt: src f32 [R][C] -> dst bf16 [C][R] (R,C multiples of 64) ----------
__global__ __launch_bounds__(256) void k_trcvt(const float* __restrict__ src,
    unsigned short* __restrict__ dst, int R, int C){
  __shared__ float tile[64][65];
  int ctiles = C >> 6;
  int rt = blockIdx.x / ctiles, ct = blockIdx.x % ctiles;
  int r0 = rt<<6, c0 = ct<<6;
  int tid = threadIdx.x;
  int lr = tid>>6, lc = tid&63;
  #pragma unroll
  for(int i=0;i<16;i++)
    tile[lr + i*4][lc] = src[(size_t)(r0+lr+i*4)*C + c0+lc];
  __syncthreads();
  #pragma unroll
  for(int i=0;i<16;i++)
    dst[(size_t)(c0+lr+i*4)*R + r0+lc] = f2bf(tile[lc][lr+i*4]);
}

// ---------- MFMA helpers ----------
DI f32x4 mfma16(short8v a, short8v b, f32x4 c){
  return __builtin_amdgcn_mfma_f32_16x16x32_bf16(a, b, c, 0, 0, 0);
}

// stage a 128x64 bf16 tile into linear LDS via global_load_lds, source pre-swizzled
// so that read-side XOR (chunk ^ (row&7)) lands on the right data.
DI void stageG(const unsigned short* __restrict__ g, size_t row0, size_t ldk,
               size_t k0, unsigned short* lds, int tid){
  int wv = tid>>6;
  #pragma unroll
  for(int i=0;i<4;i++){
    int e = i*256 + tid;          // 16B-chunk index 0..1023
    int r = e>>3, c = e&7;
    int cs = c ^ (r&7);
    const unsigned short* gp = g + (row0 + (size_t)r)*ldk + k0 + (size_t)cs*8;
    unsigned short* lp = lds + (size_t)(i*256 + wv*64)*8;   // wave-uniform base
    __builtin_amdgcn_global_load_lds((gp1_t)(const void*)gp, (lp3_t)(void*)lp, 16, 0, 0);
  }
}

// read one A/B fragment from swizzled [128][64] tile
DI short8v frag(const unsigned short* lds, int row, int chunk){
  int byte = (row<<7) + (((chunk ^ (row&7)))<<4);
  return *(const short8v*)((const char*)lds + byte);
}

// 128x128 tile, one BK=64 buffer: 4 waves in 2x2 grid, acc[4][4]
DI void mma64(const unsigned short* lsA, const unsigned short* lsB,
              int wm, int wn, int lane, f32x4 acc[4][4]){
  int r15 = lane&15, q4 = lane>>4;
  #pragma unroll
  for(int ks=0; ks<2; ks++){
    short8v a[4], b[4];
    #pragma unroll
    for(int i=0;i<4;i++){
      a[i] = frag(lsA, wm*64 + i*16 + r15, ks*4 + q4);
      b[i] = frag(lsB, wn*64 + i*16 + r15, ks*4 + q4);
    }
    #pragma unroll
    for(int mi=0;mi<4;mi++)
      #pragma unroll
      for(int ni=0;ni<4;ni++)
        acc[mi][ni] = mfma16(a[mi], b[ni], acc[mi][ni]);
  }
}

// XCD-affinity remap: consecutive logical blocks land on one XCD (nwg % 8 == 0).
DI int xcd_remap(int bid, int nwg){
  return ((bid & 7) * (nwg >> 3)) + (bid >> 3);
}

// ---------- K2: params GEMM via MFMA: par = qfb @ wpgT^T + b_pg ----------
// single-buffered BK=64 (32 KB LDS) -> 4 blocks/CU
__global__ __launch_bounds__(256, 4) void k_pgemm_mfma(const unsigned short* __restrict__ qfb,
    const unsigned short* __restrict__ wpgT, const float* __restrict__ b_pg,
    unsigned short* __restrict__ par, int qbase, int qlim, int mtiles){
  __shared__ unsigned short lsA[128*64], lsB[128*64];
  int bid = xcd_remap(blockIdx.x, gridDim.x);
  int mt = bid % mtiles, nt = bid / mtiles;
  size_t m0 = (size_t)mt*128, n0 = (size_t)nt*128;
  int tid = threadIdx.x, lane = tid&63, wv = tid>>6;
  int wm = wv>>1, wn = wv&1;
  f32x4 acc[4][4] = {};
  #pragma unroll
  for(int kb=0; kb<4; kb++){
    stageG(qfb,  qbase+m0, 256, (size_t)kb*64, lsA, tid);
    stageG(wpgT, n0,       256, (size_t)kb*64, lsB, tid);
    __syncthreads();
    mma64(lsA, lsB, wm, wn, lane, acc);
    __syncthreads();
  }
  int r15 = lane&15, q4 = lane>>4;
  #pragma unroll
  for(int ni=0; ni<4; ni++){
    int col = (int)n0 + wn*64 + ni*16 + r15;
    float bias = b_pg[col];
    #pragma unroll
    for(int mi=0; mi<4; mi++){
      #pragma unroll
      for(int j=0; j<4; j++){
        int rl = (int)m0 + wm*64 + mi*16 + q4*4 + j;
        if(qbase + rl < qlim)
          par[(size_t)rl*GTOT + col] = f2bf(acc[mi][ni][j] + bias);
      }
    }
  }
}

// ---------- K4: final GEMM via MFMA, K-split x kspl -> f32 partials ----------
// nt innermost so the two blocks sharing an A-slice are XCD-adjacent (A read once).
__global__ __launch_bounds__(256, 4) void k_fgemm_mfma(const unsigned short* __restrict__ A,
    const unsigned short* __restrict__ woutT, float* __restrict__ part,
    int qbase, int qlim, int mtiles, int kspl){
  __shared__ unsigned short lsA[128*64], lsB[128*64];
  int bid = xcd_remap(blockIdx.x, gridDim.x);
  int nt = bid & 1;
  int r2 = bid >> 1;
  int mt = r2 % mtiles, ks = r2 / mtiles;
  size_t m0 = (size_t)mt*128, n0 = (size_t)nt*128;
  int tid = threadIdx.x, lane = tid&63, wv = tid>>6;
  int wm = wv>>1, wn = wv&1;
  f32x4 acc[4][4] = {};
  int klen = GTOT / kspl;
  size_t kbase = (size_t)ks*klen;
  for(int kb=0; kb<klen/64; kb++){
    stageG(A,     m0, GTOT, kbase + (size_t)kb*64, lsA, tid);
    stageG(woutT, n0, GTOT, kbase + (size_t)kb*64, lsB, tid);
    __syncthreads();
    mma64(lsA, lsB, wm, wn, lane, acc);
    __syncthreads();
  }
  float* pp = part + (size_t)ks*NQ*256;
  int r15 = lane&15, q4 = lane>>4;
  #pragma unroll
  for(int mi=0; mi<4; mi++){
    #pragma unroll
    for(int j=0; j<4; j++){
      int rl = (int)m0 + wm*64 + mi*16 + q4*4 + j;
      int q = qbase + rl;
      if(q < qlim){
        #pragma unroll
        for(int ni=0; ni<4; ni++){
          int col = (int)n0 + wn*64 + ni*16 + r15;
          pp[(size_t)q*256 + col] = acc[mi][ni][j];
        }
      }
    }
  }
}

// ---------- K3: sampling + M/S mixing via MFMA + two group-LN+relu -> out2 bf16 ----------
// NOTE: out2 may alias par — each block reads its full par slice into registers
// before any out2 store (same (lq,g) range, disjoint across blocks).
__global__ __launch_bounds__(256) void k_mix(const unsigned short* __restrict__ featT,
    const float2* __restrict__ xyb, const float4* __restrict__ lwb,
    const unsigned short* __restrict__ par, unsigned short* __restrict__ out2,
    int qbase){
  __shared__ __align__(16) char poolA[23040];
  __shared__ __align__(16) unsigned short Ss[128*40];   // S natural [o][p], pad 40
  __shared__ float red[8];
  float* offW = (float*)poolA;
  unsigned short* xs  = (unsigned short*)(poolA + 4096);
  unsigned short* Ms  = (unsigned short*)(poolA + 4096 + 4608);
  unsigned short* o1t = (unsigned short*)(poolA + 4096 + 4608 + 9216);
  unsigned short* o2s = (unsigned short*)poolA;

  int lq = blockIdx.x >> 2, g = blockIdx.x & 3;
  int q = qbase + lq;
  int b = q / NN;
  int bg = b*4 + g;
  int tid = threadIdx.x;
  int lane = tid & 63, wv = tid >> 6;

  const int HH[4] = {100,50,25,13};
  const int WW[4] = {160,80,40,20};
  const float IS[4] = {0.125f, 0.0625f, 0.03125f, 0.015625f};
  const int LO[4] = {0, 16384000, 20480000, 21504000};

  const unsigned short* pb = par + (size_t)lq*GTOT + (size_t)g*8192;
  uint4 mraw0 = *(const uint4*)(pb + tid*8);
  uint4 mraw1 = *(const uint4*)(pb + 2048 + tid*8);
  uint4 sraw0 = *(const uint4*)(pb + 4096 + tid*8);
  uint4 sraw1 = *(const uint4*)(pb + 6144 + tid*8);

  if(tid < 128){
    int p = tid >> 2, l = tid & 3;
    int pi = q*128 + g*32 + p;
    float2 xy = xyb[pi];
    float lw4 = ((const float*)lwb)[(size_t)pi*4 + l];
    int H = HH[l], W = WW[l];
    float px = xy.x*IS[l] - 0.5f;
    float py = xy.y*IS[l] - 0.5f;
    float xf = floorf(px), yf = floorf(py);
    float wx = px - xf, wy = py - yf;
    int x0 = (int)xf, y0 = (int)yf;
    int x1 = x0 + 1, y1 = y0 + 1;
    bool vx0 = (x0>=0)&&(x0<W), vx1 = (x1>=0)&&(x1<W);
    bool vy0 = (y0>=0)&&(y0<H), vy1 = (y1>=0)&&(y1<H);
    int x0c = min(max(x0,0),W-1), x1c = min(max(x1,0),W-1);
    int y0c = min(max(y0,0),H-1), y1c = min(max(y1,0),H-1);
    int base = LO[l] + bg*H*W*64;
    float* e = offW + tid*8;
    e[0] = __int_as_float(base + (y0c*W + x0c)*64);
    e[1] = __int_as_float(base + (y0c*W + x1c)*64);
    e[2] = __int_as_float(base + (y1c*W + x0c)*64);
    e[3] = __int_as_float(base + (y1c*W + x1c)*64);
    e[4] = (1.f-wx)*(1.f-wy)*lw4*(float)(vx0&&vy0);
    e[5] = wx*(1.f-wy)*lw4*(float)(vx1&&vy0);
    e[6] = (1.f-wx)*wy*lw4*(float)(vx0&&vy1);
    e[7] = wx*wy*lw4*(float)(vx1&&vy1);
  }

  {
    int idx0 = tid*8;
    int c0 = idx0>>6, d0 = idx0&63;
    *(uint4*)(Ms + c0*72 + d0) = mraw0;
    int idx1 = 2048 + tid*8;
    int c1 = idx1>>6, d1 = idx1&63;
    *(uint4*)(Ms + c1*72 + d1) = mraw1;
    int o0 = idx0>>5, p0 = idx0&31;
    *(uint4*)(Ss + o0*40 + p0) = sraw0;
    int o1_ = idx1>>5, p1 = idx1&31;
    *(uint4*)(Ss + o1_*40 + p1) = sraw1;
  }
  __syncthreads();

  #pragma unroll
  for(int i=0;i<8;i++){
    int p = wv*8 + i;
    const float* e = offW + p*32;
    float acc = 0.f;
    #pragma unroll
    for(int l=0;l<4;l++){
      const float* el = e + l*8;
      int o00 = __float_as_int(el[0]), o01 = __float_as_int(el[1]);
      int o10 = __float_as_int(el[2]), o11 = __float_as_int(el[3]);
      acc += el[4]*bf2f(featT[o00 + lane]);
      acc += el[5]*bf2f(featT[o01 + lane]);
      acc += el[6]*bf2f(featT[o10 + lane]);
      acc += el[7]*bf2f(featT[o11 + lane]);
    }
    xs[p*72 + lane] = f2bf(acc);
  }
  __syncthreads();

  int r = lane & 15, q4 = lane >> 4;

  // Phase B: out1 = x(32x64) @ M(64x64)
  {
    short8v af00 = *(const short8v*)(xs + r*72 + q4*8);
    short8v af01 = *(const short8v*)(xs + r*72 + 32 + q4*8);
    short8v af10 = *(const short8v*)(xs + (16+r)*72 + q4*8);
    short8v af11 = *(const short8v*)(xs + (16+r)*72 + 32 + q4*8);
    short8v bm0, bm1;
    #pragma unroll
    for(int j=0;j<8;j++){
      bm0[j] = (short)Ms[(8*q4+j)*72 + wv*16 + r];
      bm1[j] = (short)Ms[(32+8*q4+j)*72 + wv*16 + r];
    }
    f32x4 a0 = {}, a1 = {};
    a0 = mfma16(af00, bm0, a0); a0 = mfma16(af01, bm1, a0);
    a1 = mfma16(af10, bm0, a1); a1 = mfma16(af11, bm1, a1);

    float s = 0.f, s2 = 0.f;
    #pragma unroll
    for(int v=0;v<4;v++){ s += a0[v]+a1[v]; s2 += a0[v]*a0[v] + a1[v]*a1[v]; }
    bred256(s, s2, red, tid);
    float mean = s*(1.f/2048.f);
    float var = s2*(1.f/2048.f) - mean*mean;
    float rs = rsqrtf(var + LN_EPS);
    #pragma unroll
    for(int v=0;v<4;v++){
      float f0 = (a0[v]-mean)*rs; f0 = f0>0.f ? f0 : 0.f;
      float f1 = (a1[v]-mean)*rs; f1 = f1>0.f ? f1 : 0.f;
      o1t[(wv*16+r)*40 + 4*q4 + v] = f2bf(f0);
      o1t[(wv*16+r)*40 + 16 + 4*q4 + v] = f2bf(f1);
    }
  }
  __syncthreads();

  // Phase C: out2 = S(128x32) @ out1(32x64)
  {
    short8v sa0 = *(const short8v*)(Ss + ((wv*2+0)*16 + r)*40 + q4*8);
    short8v sa1 = *(const short8v*)(Ss + ((wv*2+1)*16 + r)*40 + q4*8);
    short8v ov0 = *(const short8v*)(o1t + (r)*40 + q4*8);
    short8v ov1 = *(const short8v*)(o1t + (16+r)*40 + q4*8);
    short8v ov2 = *(const short8v*)(o1t + (32+r)*40 + q4*8);
    short8v ov3 = *(const short8v*)(o1t + (48+r)*40 + q4*8);
    f32x4 c2[2][4] = {};
    c2[0][0] = mfma16(sa0, ov0, c2[0][0]); c2[0][1] = mfma16(sa0, ov1, c2[0][1]);
    c2[0][2] = mfma16(sa0, ov2, c2[0][2]); c2[0][3] = mfma16(sa0, ov3, c2[0][3]);
    c2[1][0] = mfma16(sa1, ov0, c2[1][0]); c2[1][1] = mfma16(sa1, ov1, c2[1][1]);
    c2[1][2] = mfma16(sa1, ov2, c2[1][2]); c2[1][3] = mfma16(sa1, ov3, c2[1][3]);

    float s = 0.f, s2 = 0.f;
    #pragma unroll
    for(int m=0;m<2;m++)
      #pragma unroll
      for(int ni=0;ni<4;ni++)
        #pragma unroll
        for(int v=0;v<4;v++){ float x = c2[m][ni][v]; s += x; s2 += x*x; }
    bred256(s, s2, red, tid);
    float mean = s*(1.f/8192.f);
    float var = s2*(1.f/8192.f) - mean*mean;
    float rs = rsqrtf(var + LN_EPS);
    #pragma unroll
    for(int m=0;m<2;m++)
      #pragma unroll
      for(int ni=0;ni<4;ni++)
        #pragma unroll
        for(int v=0;v<4;v++){
          float x = (c2[m][ni][v]-mean)*rs; x = x>0.f ? x : 0.f;
          int o = (wv*2+m)*16 + 4*q4 + v;
          int d = ni*16 + r;
          o2s[o*72 + d] = f2bf(x);
        }
  }
  __syncthreads();

  unsigned short* og = out2 + (size_t)lq*GTOT + (size_t)g*8192;
  #pragma unroll
  for(int i=0;i<32;i++){
    int row = wv*32 + i;
    og[row*64 + lane] = o2s[row*72 + lane];
  }
}

// ---------- K5: K-split reduce + bias + residual + LayerNorm ----------
__global__ __launch_bounds__(256) void k_ln(const float* __restrict__ part,
    const float* __restrict__ qf, const float* __restrict__ b_out,
    const float* __restrict__ ln_g, const float* __restrict__ ln_b,
    float* __restrict__ out, int kspl){
  __shared__ float red[8];
  int q = blockIdx.x, j = threadIdx.x;
  float s = qf[(size_t)q*256 + j] + b_out[j];
  for(int ks=0; ks<kspl; ks++) s += part[((size_t)ks*NQ + q)*256 + j];
  float a = s, a2 = s*s;
  bred256(a, a2, red, j);
  float mean = a*(1.f/256.f);
  float var = a2*(1.f/256.f) - mean*mean;
  float rs = rsqrtf(var + LN_EPS);
  out[(size_t)q*256 + j] = (s-mean)*rs*ln_g[j] + ln_b[j];
}

// ---------- launch ----------
extern "C" void kernel_launch(void* const* d_in, const int* in_sizes, int n_in,
                              void* d_out, int out_size, void* d_ws, size_t ws_size,
                              hipStream_t stream) {
  const float* feat0 = (const float*)d_in[0];
  const float* feat1 = (const float*)d_in[1];
  const float* feat2 = (const float*)d_in[2];
  const float* feat3 = (const float*)d_in[3];
  const float* qf    = (const float*)d_in[4];
  const float* xyzr  = (const float*)d_in[5];
  const float* w_off = (const float*)d_in[6];
  const float* b_off = (const float*)d_in[7];
  const float* w_pg  = (const float*)d_in[8];
  const float* b_pg  = (const float*)d_in[9];
  const float* w_out = (const float*)d_in[10];
  const float* b_out = (const float*)d_in[11];
  const float* ln_g  = (const float*)d_in[12];
  const float* ln_b  = (const float*)d_in[13];

  // candidate configs: (K-split, chunk count) in preference order
  const int cand_ksp[5] = {32,16,16,16,16};
  const int cand_nc [5] = { 1, 1, 2, 4, 8};
  int KSP=0, NC=0, qcount=0, qpad=0;
  size_t oFEAT=0,oXY=0,oLW=0,oPART=0,oQFB=0,oWPGT=0,oWOUT=0,oPAR=0;
  for(int ci=0; ci<5; ci++){
    size_t o = 0;
    auto al = [&](size_t bytes){ size_t r = o; o = (o + bytes + 255) & ~255ull; return r; };
    size_t tFEAT = al(43540480ull);
    size_t tXY   = al((size_t)NQ*128*8);
    size_t tLW   = al((size_t)NQ*128*16);
    size_t tPART = al((size_t)cand_ksp[ci]*NQ*256*4);
    size_t tQFB  = al((size_t)2048*256*2);
    size_t tWPGT = al((size_t)GTOT*256*2);
    size_t tWOUT = al((size_t)256*GTOT*2);
    int qc = NQ / cand_nc[ci];
    int qp = (qc + 127) & ~127;
    size_t tPAR = al((size_t)qp*GTOT*2);
    if(o <= ws_size){
      KSP=cand_ksp[ci]; NC=cand_nc[ci]; qcount=qc; qpad=qp;
      oFEAT=tFEAT; oXY=tXY; oLW=tLW; oPART=tPART; oQFB=tQFB; oWPGT=tWPGT; oWOUT=tWOUT; oPAR=tPAR;
      break;
    }
  }
  if(NC == 0) return;

  char* ws = (char*)d_ws;
  unsigned short* featT = (unsigned short*)(ws + oFEAT);
  float2* xyb = (float2*)(ws + oXY);
  float4* lwb = (float4*)(ws + oLW);
  float* part = (float*)(ws + oPART);
  unsigned short* qfb  = (unsigned short*)(ws + oQFB);
  unsigned short* wpgT = (unsigned short*)(ws + oWPGT);
  unsigned short* woutT= (unsigned short*)(ws + oWOUT);
  unsigned short* par  = (unsigned short*)(ws + oPAR);
  unsigned short* o2   = par;   // aliased

  k_transpose<<<16*100, 256, 0, stream>>>(feat0, featT + 0ull,        100, 160);
  k_transpose<<<16*50,  256, 0, stream>>>(feat1, featT + 16384000ull,  50,  80);
  k_transpose<<<16*25,  256, 0, stream>>>(feat2, featT + 20480000ull,  25,  40);
  k_transpose<<<16*13,  256, 0, stream>>>(feat3, featT + 21504000ull,  13,  20);
  k_off<<<250, 384, 0, stream>>>(qf, xyzr, w_off, b_off, xyb, lwb);
  k_cvtqf<<<256, 256, 0, stream>>>(qf, qfb);
  k_trcvt<<<2048, 256, 0, stream>>>(w_pg,  wpgT, 256, GTOT);   // [256][32768] -> [32768][256]
  k_trcvt<<<2048, 256, 0, stream>>>(w_out, woutT, GTOT, 256);  // [32768][256] -> [256][32768]

  int mtiles = qpad / 128;
  for (int c = 0; c < NC; ++c) {
    int qbase = c * qcount;
    int qlim  = qbase + qcount;
    k_pgemm_mfma<<<mtiles*256, 256, 0, stream>>>(qfb, wpgT, b_pg, par, qbase, qlim, mtiles);
    k_mix<<<qcount*4, 256, 0, stream>>>(featT, xyb, lwb, par, o2, qbase);
    k_fgemm_mfma<<<mtiles*2*KSP, 256, 0, stream>>>(o2, woutT, part, qbase, qlim, mtiles, KSP);
  }
  k_ln<<<NQ, 256, 0, stream>>>(part, qf, b_out, ln_g, ln_b, (float*)d_out, KSP);
}

// Round 8
// 333.287 us; speedup vs baseline: 1.1908x; 1.1587x over previous
//
#include <hip/hip_runtime.h>
#include <hip/hip_bf16.h>
#include <cstdint>
#include <cstddef>

#define DI __device__ __forceinline__

// ---------- constants ----------
#define NN 500
#define NQ 2000           // B*N
#define GTOT 32768        // G*TOTAL
#define LN_EPS 1e-5f

typedef __attribute__((ext_vector_type(8))) short short8v;
typedef __attribute__((ext_vector_type(4))) float f32x4;
typedef const __attribute__((address_space(1))) void* gp1_t;
typedef __attribute__((address_space(3))) void* lp3_t;

DI unsigned short f2bf(float f){
  unsigned u = __float_as_uint(f);
  return (unsigned short)((u + 0x7fffu + ((u>>16)&1u)) >> 16);
}
DI float bf2f(unsigned short s){ return __uint_as_float(((unsigned)s)<<16); }

// block-wide (256 thr = 4 waves) sum of s, s2
DI void bred256(float& s, float& s2, float* red, int tid){
  #pragma unroll
  for(int off=32; off; off>>=1){
    s  += __shfl_xor(s,  off, 64);
    s2 += __shfl_xor(s2, off, 64);
  }
  int w = tid>>6;
  if((tid&63)==0){ red[w*2]=s; red[w*2+1]=s2; }
  __syncthreads();
  s  = red[0]+red[2]+red[4]+red[6];
  s2 = red[1]+red[3]+red[5]+red[7];
  __syncthreads();
}

// ---------- K0: feature transpose (B,C,H,W) f32 -> (B*G,H,W,64) bf16 ----------
__global__ __launch_bounds__(256) void k_transpose(const float* __restrict__ src,
    unsigned short* __restrict__ dst, int H, int W){
  __shared__ float tile[64][161];
  int bg = blockIdx.x / H, h = blockIdx.x % H;
  int b = bg >> 2, g = bg & 3;
  const float* s = src + (((size_t)(b*256 + g*64))*H + h)*(size_t)W;
  for(int idx=threadIdx.x; idx<64*W; idx+=256){
    int c = idx / W, w = idx - c*W;
    tile[c][w] = s[(size_t)c*H*W + w];
  }
  __syncthreads();
  unsigned short* d = dst + ((size_t)bg*H + h)*(size_t)W*64;
  for(int idx=threadIdx.x; idx<64*W; idx+=256){
    int w = idx>>6, c = idx&63;
    d[idx] = f2bf(tile[c][w]);
  }
}

// ---------- K1: offset GEMM + sample coords + level softmax ----------
__global__ __launch_bounds__(384) void k_off(const float* __restrict__ qf,
    const float* __restrict__ xyzr, const float* __restrict__ w_off,
    const float* __restrict__ b_off, float2* __restrict__ xyb, float4* __restrict__ lwb){
  __shared__ float qs[8][256];
  __shared__ float os[8][384];
  int q0 = blockIdx.x*8, tid = threadIdx.x;
  for(int idx=tid; idx<2048; idx+=384){
    int qq = idx>>8, k = idx&255;
    qs[qq][k] = qf[(size_t)(q0+qq)*256 + k];
  }
  __syncthreads();
  {
    int j = tid;
    float acc[8];
    #pragma unroll
    for(int i=0;i<8;i++) acc[i]=0.f;
    for(int k=0;k<256;k++){
      float w = w_off[(size_t)k*384 + j];
      #pragma unroll
      for(int qq=0;qq<8;qq++) acc[qq] += qs[qq][k]*w;
    }
    float bb = b_off[j];
    #pragma unroll
    for(int qq=0;qq<8;qq++) os[qq][j] = acc[qq] + bb;
  }
  __syncthreads();
  for(int idx=tid; idx<1024; idx+=384){
    int qq = idx>>7, gp = idx&127;
    int q = q0+qq;
    float4 xr = *(const float4*)&xyzr[(size_t)q*4];
    float rw = exp2f(xr.z - 0.5f*xr.w);
    float rh = exp2f(xr.z + 0.5f*xr.w);
    float sx = xr.x + os[qq][gp*3+0]*rw;
    float sy = xr.y + os[qq][gp*3+1]*rh;
    float lvl = xr.z + os[qq][gp*3+2] - 3.0f;
    float d0=lvl, d1=lvl-1.f, d2=lvl-2.f, d3=lvl-3.f;
    float e0=-0.5f*d0*d0, e1=-0.5f*d1*d1, e2=-0.5f*d2*d2, e3=-0.5f*d3*d3;
    float m = fmaxf(fmaxf(e0,e1),fmaxf(e2,e3));
    float x0=expf(e0-m), x1=expf(e1-m), x2=expf(e2-m), x3=expf(e3-m);
    float inv = 1.f/(x0+x1+x2+x3);
    xyb[(size_t)q*128+gp] = make_float2(sx,sy);
    lwb[(size_t)q*128+gp] = make_float4(x0*inv, x1*inv, x2*inv, x3*inv);
  }
}

// ---------- K-cvt: qf f32[2000][256] -> bf16[2048][256], pad rows zeroed ----------
__global__ __launch_bounds__(256) void k_cvtqf(const float* __restrict__ qf,
    unsigned short* __restrict__ qfb){
  int idx = blockIdx.x*256 + threadIdx.x;   // one per 8 elems; 65536 total
  size_t base = (size_t)idx*8;
  int row = idx >> 5;
  ushort4 lo, hi;
  if(row < NQ){
    float4 a = *(const float4*)(qf + base);
    float4 b = *(const float4*)(qf + base + 4);
    lo.x=f2bf(a.x); lo.y=f2bf(a.y); lo.z=f2bf(a.z); lo.w=f2bf(a.w);
    hi.x=f2bf(b.x); hi.y=f2bf(b.y); hi.z=f2bf(b.z); hi.w=f2bf(b.w);
  } else {
    lo.x=lo.y=lo.z=lo.w=0; hi.x=hi.y=hi.z=hi.w=0;
  }
  *(ushort4*)(qfb + base) = lo;
  *(ushort4*)(qfb + base + 4) = hi;
}

// ---------- K-trcvt: src f32 [R][C] -> dst bf16 [C][R] (R,C multiples of 64) ----------
__global__ __launch_bounds__(256) void k_trcvt(const float* __restrict__ src,
    unsigned short* __restrict__ dst, int R, int C){
  __shared__ float tile[64][65];
  int ctiles = C >> 6;
  int rt = blockIdx.x / ctiles, ct = blockIdx.x % ctiles;
  int r0 = rt<<6, c0 = ct<<6;
  int tid = threadIdx.x;
  int lr = tid>>6, lc = tid&63;
  #pragma unroll
  for(int i=0;i<16;i++)
    tile[lr + i*4][lc] = src[(size_t)(r0+lr+i*4)*C + c0+lc];
  __syncthreads();
  #pragma unroll
  for(int i=0;i<16;i++)
    dst[(size_t)(c0+lr+i*4)*R + r0+lc] = f2bf(tile[lc][lr+i*4]);
}

// ---------- MFMA helpers ----------
DI f32x4 mfma16(short8v a, short8v b, f32x4 c){
  return __builtin_amdgcn_mfma_f32_16x16x32_bf16(a, b, c, 0, 0, 0);
}

// swizzle for [128][32]-short tiles: chunk c (16B) XOR row bits -> bank-balanced b128 reads
DI int swz32(int c, int r){ return c ^ (r&3) ^ ((r>>2)&3); }

// stage a 128x32 bf16 tile into linear LDS via global_load_lds, source pre-swizzled.
DI void stageG32(const unsigned short* __restrict__ g, size_t row0, size_t ldk,
                 size_t k0, unsigned short* lds, int tid){
  int wv = tid>>6;
  #pragma unroll
  for(int i=0;i<2;i++){
    int e = i*256 + tid;          // 16B-chunk index 0..511
    int r = e>>2, c = e&3;
    int cs = swz32(c, r);
    const unsigned short* gp = g + (row0 + (size_t)r)*ldk + k0 + (size_t)cs*8;
    unsigned short* lp = lds + (size_t)(i*256 + wv*64)*8;   // wave-uniform base
    __builtin_amdgcn_global_load_lds((gp1_t)(const void*)gp, (lp3_t)(void*)lp, 16, 0, 0);
  }
}

// read one A/B fragment (row, k-chunk q4) from swizzled [128][32] tile
DI short8v frag32(const unsigned short* lds, int row, int q4){
  return *(const short8v*)(lds + (size_t)row*32 + (size_t)swz32(q4, row)*8);
}

// one BK=32 step: 4 A-frags, 4 B-frags, 16 MFMA
DI void mma32(const unsigned short* lsA, const unsigned short* lsB,
              int wm, int wn, int lane, f32x4 acc[4][4]){
  int r15 = lane&15, q4 = lane>>4;
  short8v a[4], b[4];
  #pragma unroll
  for(int i=0;i<4;i++){
    a[i] = frag32(lsA, wm*64 + i*16 + r15, q4);
    b[i] = frag32(lsB, wn*64 + i*16 + r15, q4);
  }
  #pragma unroll
  for(int mi=0;mi<4;mi++)
    #pragma unroll
    for(int ni=0;ni<4;ni++)
      acc[mi][ni] = mfma16(a[mi], b[ni], acc[mi][ni]);
}

// XCD-affinity remap: consecutive logical blocks land on one XCD (nwg % 8 == 0).
DI int xcd_remap(int bid, int nwg){
  return ((bid & 7) * (nwg >> 3)) + (bid >> 3);
}

// ---------- K2: params GEMM via MFMA: par = qfb @ wpgT^T + b_pg ----------
// 2-phase pipelined dbuf BK=32 (32 KB LDS) -> 4 blocks/CU; LDS-staged coalesced epilogue.
__global__ __launch_bounds__(256, 4) void k_pgemm_mfma(const unsigned short* __restrict__ qfb,
    const unsigned short* __restrict__ wpgT, const float* __restrict__ b_pg,
    unsigned short* __restrict__ par, int qbase, int qlim, int mtiles){
  __shared__ unsigned short pool[16384];     // 32 KB
  int bid = xcd_remap(blockIdx.x, gridDim.x);
  int mt = bid % mtiles, nt = bid / mtiles;
  size_t m0 = (size_t)mt*128, n0 = (size_t)nt*128;
  int tid = threadIdx.x, lane = tid&63, wv = tid>>6;
  int wm = wv>>1, wn = wv&1;
  int r15 = lane&15, q4 = lane>>4;
  f32x4 acc[4][4] = {};
  stageG32(qfb,  qbase+m0, 256, 0, pool, tid);
  stageG32(wpgT, n0,       256, 0, pool + 8192, tid);
  __syncthreads();
  #pragma unroll
  for(int t=0; t<8; t++){
    int co = (t&1)*4096;
    if(t<7){
      int no = ((t&1)^1)*4096;
      stageG32(qfb,  qbase+m0, 256, (size_t)(t+1)*32, pool + no, tid);
      stageG32(wpgT, n0,       256, (size_t)(t+1)*32, pool + 8192 + no, tid);
    }
    mma32(pool + co, pool + 8192 + co, wm, wn, lane, acc);
    __syncthreads();
  }
  // epilogue: stage bf16 result in LDS [128][72], store full 128B rows, two col-halves
  unsigned short* es = pool;
  #pragma unroll
  for(int h=0; h<2; ++h){
    if(h) __syncthreads();
    if(wn == h){
      #pragma unroll
      for(int ni=0; ni<4; ni++){
        float bias = b_pg[(int)n0 + wn*64 + ni*16 + r15];
        #pragma unroll
        for(int mi=0; mi<4; mi++)
          #pragma unroll
          for(int j=0; j<4; j++){
            int row = wm*64 + mi*16 + q4*4 + j;
            es[row*72 + ni*16 + r15] = f2bf(acc[mi][ni][j] + bias);
          }
      }
    }
    __syncthreads();
    #pragma unroll
    for(int i=0;i<4;i++){
      int e = i*256 + tid;              // 1024 chunks of 8 shorts
      int row = e>>3, c8 = (e&7)*8;
      int rl = (int)m0 + row;
      if(qbase + rl < qlim){
        uint4 v = *(const uint4*)(es + row*72 + c8);
        *(uint4*)&par[(size_t)rl*GTOT + n0 + h*64 + c8] = v;
      }
    }
  }
}

// ---------- K4: final GEMM via MFMA, K-split x kspl -> f32 partials ----------
// 2-phase pipelined dbuf BK=32; nt innermost so A-slice-sharing blocks are XCD-adjacent.
__global__ __launch_bounds__(256, 4) void k_fgemm_mfma(const unsigned short* __restrict__ Ag,
    const unsigned short* __restrict__ woutT, float* __restrict__ part,
    int qbase, int qlim, int mtiles, int kspl){
  __shared__ unsigned short pool[16384];
  int bid = xcd_remap(blockIdx.x, gridDim.x);
  int nt = bid & 1;
  int r2 = bid >> 1;
  int mt = r2 % mtiles, ks = r2 / mtiles;
  size_t m0 = (size_t)mt*128, n0 = (size_t)nt*128;
  int tid = threadIdx.x, lane = tid&63, wv = tid>>6;
  int wm = wv>>1, wn = wv&1;
  f32x4 acc[4][4] = {};
  int klen = GTOT / kspl;
  size_t kbase = (size_t)ks*klen;
  int NT = klen >> 5;
  stageG32(Ag,    m0, GTOT, kbase, pool, tid);
  stageG32(woutT, n0, GTOT, kbase, pool + 8192, tid);
  __syncthreads();
  for(int t=0; t<NT; t++){
    int co = (t&1)*4096;
    if(t+1<NT){
      int no = ((t&1)^1)*4096;
      stageG32(Ag,    m0, GTOT, kbase + (size_t)(t+1)*32, pool + no, tid);
      stageG32(woutT, n0, GTOT, kbase + (size_t)(t+1)*32, pool + 8192 + no, tid);
    }
    mma32(pool + co, pool + 8192 + co, wm, wn, lane, acc);
    __syncthreads();
  }
  float* pp = part + (size_t)ks*NQ*256;
  int r15 = lane&15, q4 = lane>>4;
  #pragma unroll
  for(int mi=0; mi<4; mi++){
    #pragma unroll
    for(int j=0; j<4; j++){
      int rl = (int)m0 + wm*64 + mi*16 + q4*4 + j;
      int q = qbase + rl;
      if(q < qlim){
        #pragma unroll
        for(int ni=0; ni<4; ni++){
          int col = (int)n0 + wn*64 + ni*16 + r15;
          pp[(size_t)q*256 + col] = acc[mi][ni][j];
        }
      }
    }
  }
}

// ---------- K3: sampling + M/S mixing via MFMA + two group-LN+relu -> out2 bf16 ----------
// NOTE: out2 may alias par — each block reads its full par slice into registers
// before any out2 store (same (lq,g) range, disjoint across blocks).
__global__ __launch_bounds__(256) void k_mix(const unsigned short* __restrict__ featT,
    const float2* __restrict__ xyb, const float4* __restrict__ lwb,
    const unsigned short* __restrict__ par, unsigned short* __restrict__ out2,
    int qbase){
  __shared__ __align__(16) char poolA[23040];
  __shared__ __align__(16) unsigned short Ss[128*40];   // S natural [o][p], pad 40
  __shared__ float red[8];
  float* offW = (float*)poolA;
  unsigned short* xs  = (unsigned short*)(poolA + 4096);
  unsigned short* Ms  = (unsigned short*)(poolA + 4096 + 4608);
  unsigned short* o1t = (unsigned short*)(poolA + 4096 + 4608 + 9216);
  unsigned short* o2s = (unsigned short*)poolA;

  int lq = blockIdx.x >> 2, g = blockIdx.x & 3;
  int q = qbase + lq;
  int b = q / NN;
  int bg = b*4 + g;
  int tid = threadIdx.x;
  int lane = tid & 63, wv = tid >> 6;

  const int HH[4] = {100,50,25,13};
  const int WW[4] = {160,80,40,20};
  const float IS[4] = {0.125f, 0.0625f, 0.03125f, 0.015625f};
  const int LO[4] = {0, 16384000, 20480000, 21504000};

  const unsigned short* pb = par + (size_t)lq*GTOT + (size_t)g*8192;
  uint4 mraw0 = *(const uint4*)(pb + tid*8);
  uint4 mraw1 = *(const uint4*)(pb + 2048 + tid*8);
  uint4 sraw0 = *(const uint4*)(pb + 4096 + tid*8);
  uint4 sraw1 = *(const uint4*)(pb + 6144 + tid*8);

  if(tid < 128){
    int p = tid >> 2, l = tid & 3;
    int pi = q*128 + g*32 + p;
    float2 xy = xyb[pi];
    float lw4 = ((const float*)lwb)[(size_t)pi*4 + l];
    int H = HH[l], W = WW[l];
    float px = xy.x*IS[l] - 0.5f;
    float py = xy.y*IS[l] - 0.5f;
    float xf = floorf(px), yf = floorf(py);
    float wx = px - xf, wy = py - yf;
    int x0 = (int)xf, y0 = (int)yf;
    int x1 = x0 + 1, y1 = y0 + 1;
    bool vx0 = (x0>=0)&&(x0<W), vx1 = (x1>=0)&&(x1<W);
    bool vy0 = (y0>=0)&&(y0<H), vy1 = (y1>=0)&&(y1<H);
    int x0c = min(max(x0,0),W-1), x1c = min(max(x1,0),W-1);
    int y0c = min(max(y0,0),H-1), y1c = min(max(y1,0),H-1);
    int base = LO[l] + bg*H*W*64;
    float* e = offW + tid*8;
    e[0] = __int_as_float(base + (y0c*W + x0c)*64);
    e[1] = __int_as_float(base + (y0c*W + x1c)*64);
    e[2] = __int_as_float(base + (y1c*W + x0c)*64);
    e[3] = __int_as_float(base + (y1c*W + x1c)*64);
    e[4] = (1.f-wx)*(1.f-wy)*lw4*(float)(vx0&&vy0);
    e[5] = wx*(1.f-wy)*lw4*(float)(vx1&&vy0);
    e[6] = (1.f-wx)*wy*lw4*(float)(vx0&&vy1);
    e[7] = wx*wy*lw4*(float)(vx1&&vy1);
  }

  {
    int idx0 = tid*8;
    int c0 = idx0>>6, d0 = idx0&63;
    *(uint4*)(Ms + c0*72 + d0) = mraw0;
    int idx1 = 2048 + tid*8;
    int c1 = idx1>>6, d1 = idx1&63;
    *(uint4*)(Ms + c1*72 + d1) = mraw1;
    int o0 = idx0>>5, p0 = idx0&31;
    *(uint4*)(Ss + o0*40 + p0) = sraw0;
    int o1_ = idx1>>5, p1 = idx1&31;
    *(uint4*)(Ss + o1_*40 + p1) = sraw1;
  }
  __syncthreads();

  #pragma unroll
  for(int i=0;i<8;i++){
    int p = wv*8 + i;
    const float* e = offW + p*32;
    float acc = 0.f;
    #pragma unroll
    for(int l=0;l<4;l++){
      const float* el = e + l*8;
      int o00 = __float_as_int(el[0]), o01 = __float_as_int(el[1]);
      int o10 = __float_as_int(el[2]), o11 = __float_as_int(el[3]);
      acc += el[4]*bf2f(featT[o00 + lane]);
      acc += el[5]*bf2f(featT[o01 + lane]);
      acc += el[6]*bf2f(featT[o10 + lane]);
      acc += el[7]*bf2f(featT[o11 + lane]);
    }
    xs[p*72 + lane] = f2bf(acc);
  }
  __syncthreads();

  int r = lane & 15, q4 = lane >> 4;

  // Phase B: out1 = x(32x64) @ M(64x64)
  {
    short8v af00 = *(const short8v*)(xs + r*72 + q4*8);
    short8v af01 = *(const short8v*)(xs + r*72 + 32 + q4*8);
    short8v af10 = *(const short8v*)(xs + (16+r)*72 + q4*8);
    short8v af11 = *(const short8v*)(xs + (16+r)*72 + 32 + q4*8);
    short8v bm0, bm1;
    #pragma unroll
    for(int j=0;j<8;j++){
      bm0[j] = (short)Ms[(8*q4+j)*72 + wv*16 + r];
      bm1[j] = (short)Ms[(32+8*q4+j)*72 + wv*16 + r];
    }
    f32x4 a0 = {}, a1 = {};
    a0 = mfma16(af00, bm0, a0); a0 = mfma16(af01, bm1, a0);
    a1 = mfma16(af10, bm0, a1); a1 = mfma16(af11, bm1, a1);

    float s = 0.f, s2 = 0.f;
    #pragma unroll
    for(int v=0;v<4;v++){ s += a0[v]+a1[v]; s2 += a0[v]*a0[v] + a1[v]*a1[v]; }
    bred256(s, s2, red, tid);
    float mean = s*(1.f/2048.f);
    float var = s2*(1.f/2048.f) - mean*mean;
    float rs = rsqrtf(var + LN_EPS);
    #pragma unroll
    for(int v=0;v<4;v++){
      float f0 = (a0[v]-mean)*rs; f0 = f0>0.f ? f0 : 0.f;
      float f1 = (a1[v]-mean)*rs; f1 = f1>0.f ? f1 : 0.f;
      o1t[(wv*16+r)*40 + 4*q4 + v] = f2bf(f0);
      o1t[(wv*16+r)*40 + 16 + 4*q4 + v] = f2bf(f1);
    }
  }
  __syncthreads();

  // Phase C: out2 = S(128x32) @ out1(32x64)
  {
    short8v sa0 = *(const short8v*)(Ss + ((wv*2+0)*16 + r)*40 + q4*8);
    short8v sa1 = *(const short8v*)(Ss + ((wv*2+1)*16 + r)*40 + q4*8);
    short8v ov0 = *(const short8v*)(o1t + (r)*40 + q4*8);
    short8v ov1 = *(const short8v*)(o1t + (16+r)*40 + q4*8);
    short8v ov2 = *(const short8v*)(o1t + (32+r)*40 + q4*8);
    short8v ov3 = *(const short8v*)(o1t + (48+r)*40 + q4*8);
    f32x4 c2[2][4] = {};
    c2[0][0] = mfma16(sa0, ov0, c2[0][0]); c2[0][1] = mfma16(sa0, ov1, c2[0][1]);
    c2[0][2] = mfma16(sa0, ov2, c2[0][2]); c2[0][3] = mfma16(sa0, ov3, c2[0][3]);
    c2[1][0] = mfma16(sa1, ov0, c2[1][0]); c2[1][1] = mfma16(sa1, ov1, c2[1][1]);
    c2[1][2] = mfma16(sa1, ov2, c2[1][2]); c2[1][3] = mfma16(sa1, ov3, c2[1][3]);

    float s = 0.f, s2 = 0.f;
    #pragma unroll
    for(int m=0;m<2;m++)
      #pragma unroll
      for(int ni=0;ni<4;ni++)
        #pragma unroll
        for(int v=0;v<4;v++){ float x = c2[m][ni][v]; s += x; s2 += x*x; }
    bred256(s, s2, red, tid);
    float mean = s*(1.f/8192.f);
    float var = s2*(1.f/8192.f) - mean*mean;
    float rs = rsqrtf(var + LN_EPS);
    #pragma unroll
    for(int m=0;m<2;m++)
      #pragma unroll
      for(int ni=0;ni<4;ni++)
        #pragma unroll
        for(int v=0;v<4;v++){
          float x = (c2[m][ni][v]-mean)*rs; x = x>0.f ? x : 0.f;
          int o = (wv*2+m)*16 + 4*q4 + v;
          int d = ni*16 + r;
          o2s[o*72 + d] = f2bf(x);
        }
  }
  __syncthreads();

  unsigned short* og = out2 + (size_t)lq*GTOT + (size_t)g*8192;
  #pragma unroll
  for(int i=0;i<32;i++){
    int row = wv*32 + i;
    og[row*64 + lane] = o2s[row*72 + lane];
  }
}

// ---------- K5: K-split reduce + bias + residual + LayerNorm ----------
__global__ __launch_bounds__(256) void k_ln(const float* __restrict__ part,
    const float* __restrict__ qf, const float* __restrict__ b_out,
    const float* __restrict__ ln_g, const float* __restrict__ ln_b,
    float* __restrict__ out, int kspl){
  __shared__ float red[8];
  int q = blockIdx.x, j = threadIdx.x;
  float s = qf[(size_t)q*256 + j] + b_out[j];
  for(int ks=0; ks<kspl; ks++) s += part[((size_t)ks*NQ + q)*256 + j];
  float a = s, a2 = s*s;
  bred256(a, a2, red, j);
  float mean = a*(1.f/256.f);
  float var = a2*(1.f/256.f) - mean*mean;
  float rs = rsqrtf(var + LN_EPS);
  out[(size_t)q*256 + j] = (s-mean)*rs*ln_g[j] + ln_b[j];
}

// ---------- launch ----------
extern "C" void kernel_launch(void* const* d_in, const int* in_sizes, int n_in,
                              void* d_out, int out_size, void* d_ws, size_t ws_size,
                              hipStream_t stream) {
  const float* feat0 = (const float*)d_in[0];
  const float* feat1 = (const float*)d_in[1];
  const float* feat2 = (const float*)d_in[2];
  const float* feat3 = (const float*)d_in[3];
  const float* qf    = (const float*)d_in[4];
  const float* xyzr  = (const float*)d_in[5];
  const float* w_off = (const float*)d_in[6];
  const float* b_off = (const float*)d_in[7];
  const float* w_pg  = (const float*)d_in[8];
  const float* b_pg  = (const float*)d_in[9];
  const float* w_out = (const float*)d_in[10];
  const float* b_out = (const float*)d_in[11];
  const float* ln_g  = (const float*)d_in[12];
  const float* ln_b  = (const float*)d_in[13];

  // candidate configs: (K-split, chunk count) in preference order
  const int cand_ksp[5] = {32,16,16,16,16};
  const int cand_nc [5] = { 1, 1, 2, 4, 8};
  int KSP=0, NC=0, qcount=0, qpad=0;
  size_t oFEAT=0,oXY=0,oLW=0,oPART=0,oQFB=0,oWPGT=0,oWOUT=0,oPAR=0;
  for(int ci=0; ci<5; ci++){
    size_t o = 0;
    auto al = [&](size_t bytes){ size_t r = o; o = (o + bytes + 255) & ~255ull; return r; };
    size_t tFEAT = al(43540480ull);
    size_t tXY   = al((size_t)NQ*128*8);
    size_t tLW   = al((size_t)NQ*128*16);
    size_t tPART = al((size_t)cand_ksp[ci]*NQ*256*4);
    size_t tQFB  = al((size_t)2048*256*2);
    size_t tWPGT = al((size_t)GTOT*256*2);
    size_t tWOUT = al((size_t)256*GTOT*2);
    int qc = NQ / cand_nc[ci];
    int qp = (qc + 127) & ~127;
    size_t tPAR = al((size_t)qp*GTOT*2);
    if(o <= ws_size){
      KSP=cand_ksp[ci]; NC=cand_nc[ci]; qcount=qc; qpad=qp;
      oFEAT=tFEAT; oXY=tXY; oLW=tLW; oPART=tPART; oQFB=tQFB; oWPGT=tWPGT; oWOUT=tWOUT; oPAR=tPAR;
      break;
    }
  }
  if(NC == 0) return;

  char* ws = (char*)d_ws;
  unsigned short* featT = (unsigned short*)(ws + oFEAT);
  float2* xyb = (float2*)(ws + oXY);
  float4* lwb = (float4*)(ws + oLW);
  float* part = (float*)(ws + oPART);
  unsigned short* qfb  = (unsigned short*)(ws + oQFB);
  unsigned short* wpgT = (unsigned short*)(ws + oWPGT);
  unsigned short* woutT= (unsigned short*)(ws + oWOUT);
  unsigned short* par  = (unsigned short*)(ws + oPAR);
  unsigned short* o2   = par;   // aliased

  k_transpose<<<16*100, 256, 0, stream>>>(feat0, featT + 0ull,        100, 160);
  k_transpose<<<16*50,  256, 0, stream>>>(feat1, featT + 16384000ull,  50,  80);
  k_transpose<<<16*25,  256, 0, stream>>>(feat2, featT + 20480000ull,  25,  40);
  k_transpose<<<16*13,  256, 0, stream>>>(feat3, featT + 21504000ull,  13,  20);
  k_off<<<250, 384, 0, stream>>>(qf, xyzr, w_off, b_off, xyb, lwb);
  k_cvtqf<<<256, 256, 0, stream>>>(qf, qfb);
  k_trcvt<<<2048, 256, 0, stream>>>(w_pg,  wpgT, 256, GTOT);   // [256][32768] -> [32768][256]
  k_trcvt<<<2048, 256, 0, stream>>>(w_out, woutT, GTOT, 256);  // [32768][256] -> [256][32768]

  int mtiles = qpad / 128;
  for (int c = 0; c < NC; ++c) {
    int qbase = c * qcount;
    int qlim  = qbase + qcount;
    k_pgemm_mfma<<<mtiles*256, 256, 0, stream>>>(qfb, wpgT, b_pg, par, qbase, qlim, mtiles);
    k_mix<<<qcount*4, 256, 0, stream>>>(featT, xyb, lwb, par, o2, qbase);
    k_fgemm_mfma<<<mtiles*2*KSP, 256, 0, stream>>>(o2, woutT, part, qbase, qlim, mtiles, KSP);
  }
  k_ln<<<NQ, 256, 0, stream>>>(part, qf, b_out, ln_g, ln_b, (float*)d_out, KSP);
}

// Round 9
// 320.951 us; speedup vs baseline: 1.2365x; 1.0384x over previous
//
#include <hip/hip_runtime.h>
#include <hip/hip_bf16.h>
#include <cstdint>
#include <cstddef>

#define DI __device__ __forceinline__

// ---------- constants ----------
#define NN 500
#define NQ 2000           // B*N
#define GTOT 32768        // G*TOTAL
#define LN_EPS 1e-5f

typedef __attribute__((ext_vector_type(8))) short short8v;
typedef __attribute__((ext_vector_type(4))) float f32x4;
typedef const __attribute__((address_space(1))) void* gp1_t;
typedef __attribute__((address_space(3))) void* lp3_t;

DI unsigned short f2bf(float f){
  unsigned u = __float_as_uint(f);
  return (unsigned short)((u + 0x7fffu + ((u>>16)&1u)) >> 16);
}
DI float bf2f(unsigned short s){ return __uint_as_float(((unsigned)s)<<16); }

// block-wide (256 thr = 4 waves) sum of s, s2
DI void bred256(float& s, float& s2, float* red, int tid){
  #pragma unroll
  for(int off=32; off; off>>=1){
    s  += __shfl_xor(s,  off, 64);
    s2 += __shfl_xor(s2, off, 64);
  }
  int w = tid>>6;
  if((tid&63)==0){ red[w*2]=s; red[w*2+1]=s2; }
  __syncthreads();
  s  = red[0]+red[2]+red[4]+red[6];
  s2 = red[1]+red[3]+red[5]+red[7];
  __syncthreads();
}

// ---------- K-prep: fused prepasses (block-range switch, 256 thr) ----------
// [0,3008)      feature transpose (B,C,H,W) f32 -> (B*G,H,W,64) bf16
// [3008,3264)   qf f32 -> bf16 [2048][256] (pad rows zeroed)
// [3264,5312)   w_pg  [256][32768] -> wpgT  [32768][256] bf16
// [5312,7360)   w_out [32768][256] -> woutT [256][32768] bf16
// [7360,7610)   offset GEMM + sample coords + level softmax
__global__ __launch_bounds__(256) void k_prep(
    const float* __restrict__ f0, const float* __restrict__ f1,
    const float* __restrict__ f2, const float* __restrict__ f3,
    const float* __restrict__ qf, const float* __restrict__ xyzr,
    const float* __restrict__ w_off, const float* __restrict__ b_off,
    const float* __restrict__ w_pg, const float* __restrict__ w_out,
    unsigned short* __restrict__ featT, float2* __restrict__ xyb,
    float4* __restrict__ lwb, unsigned short* __restrict__ qfb,
    unsigned short* __restrict__ wpgT, unsigned short* __restrict__ woutT){
  __shared__ __align__(16) char P[41216];
  int bid = blockIdx.x, tid = threadIdx.x;

  if(bid < 3008){
    // ---- transpose ----
    const float* src; unsigned short* dst; int H, W, lb;
    if(bid < 1600){ src=f0; dst=featT;            H=100; W=160; lb=bid; }
    else if(bid < 2400){ src=f1; dst=featT+16384000; H=50; W=80; lb=bid-1600; }
    else if(bid < 2800){ src=f2; dst=featT+20480000; H=25; W=40; lb=bid-2400; }
    else { src=f3; dst=featT+21504000; H=13; W=20; lb=bid-2800; }
    float (*tile)[161] = (float(*)[161])P;
    int bg = lb / H, h = lb % H;
    int b = bg >> 2, g = bg & 3;
    const float* s = src + (((size_t)(b*256 + g*64))*H + h)*(size_t)W;
    for(int idx=tid; idx<64*W; idx+=256){
      int c = idx / W, w = idx - c*W;
      tile[c][w] = s[(size_t)c*H*W + w];
    }
    __syncthreads();
    unsigned short* d = dst + ((size_t)bg*H + h)*(size_t)W*64;
    for(int idx=tid; idx<64*W; idx+=256){
      int w = idx>>6, c = idx&63;
      d[idx] = f2bf(tile[c][w]);
    }
  } else if(bid < 3264){
    // ---- qf -> bf16 padded ----
    int idx = (bid-3008)*256 + tid;
    size_t base = (size_t)idx*8;
    int row = idx >> 5;
    ushort4 lo, hi;
    if(row < NQ){
      float4 a = *(const float4*)(qf + base);
      float4 b = *(const float4*)(qf + base + 4);
      lo.x=f2bf(a.x); lo.y=f2bf(a.y); lo.z=f2bf(a.z); lo.w=f2bf(a.w);
      hi.x=f2bf(b.x); hi.y=f2bf(b.y); hi.z=f2bf(b.z); hi.w=f2bf(b.w);
    } else {
      lo.x=lo.y=lo.z=lo.w=0; hi.x=hi.y=hi.z=hi.w=0;
    }
    *(ushort4*)(qfb + base) = lo;
    *(ushort4*)(qfb + base + 4) = hi;
  } else if(bid < 7360){
    // ---- transpose-convert weight matrices ----
    const float* src; unsigned short* dst; int R, C, lb;
    if(bid < 5312){ src=w_pg;  dst=wpgT;  R=256;  C=GTOT; lb=bid-3264; }
    else          { src=w_out; dst=woutT; R=GTOT; C=256;  lb=bid-5312; }
    float (*tile)[65] = (float(*)[65])P;
    int ctiles = C >> 6;
    int rt = lb / ctiles, ct = lb % ctiles;
    int r0 = rt<<6, c0 = ct<<6;
    int lr = tid>>6, lc = tid&63;
    #pragma unroll
    for(int i=0;i<16;i++)
      tile[lr + i*4][lc] = src[(size_t)(r0+lr+i*4)*C + c0+lc];
    __syncthreads();
    #pragma unroll
    for(int i=0;i<16;i++)
      dst[(size_t)(c0+lr+i*4)*R + r0+lc] = f2bf(tile[lc][lr+i*4]);
  } else {
    // ---- offset GEMM + coords + softmax (8 queries / block) ----
    float (*qs)[256] = (float(*)[256])P;
    float (*os)[384] = (float(*)[384])(P + 8192);
    int q0 = (bid-7360)*8;
    for(int idx=tid; idx<2048; idx+=256){
      int qq = idx>>8, k = idx&255;
      qs[qq][k] = qf[(size_t)(q0+qq)*256 + k];
    }
    __syncthreads();
    #pragma unroll
    for(int jj=0; jj<2; jj++){
      int j = tid + jj*256;
      if(j < 384){
        float acc[8];
        #pragma unroll
        for(int i=0;i<8;i++) acc[i]=0.f;
        for(int k=0;k<256;k++){
          float w = w_off[(size_t)k*384 + j];
          #pragma unroll
          for(int qq=0;qq<8;qq++) acc[qq] += qs[qq][k]*w;
        }
        float bb = b_off[j];
        #pragma unroll
        for(int qq=0;qq<8;qq++) os[qq][j] = acc[qq] + bb;
      }
    }
    __syncthreads();
    for(int idx=tid; idx<1024; idx+=256){
      int qq = idx>>7, gp = idx&127;
      int q = q0+qq;
      float4 xr = *(const float4*)&xyzr[(size_t)q*4];
      float rw = exp2f(xr.z - 0.5f*xr.w);
      float rh = exp2f(xr.z + 0.5f*xr.w);
      float sx = xr.x + os[qq][gp*3+0]*rw;
      float sy = xr.y + os[qq][gp*3+1]*rh;
      float lvl = xr.z + os[qq][gp*3+2] - 3.0f;
      float d0=lvl, d1=lvl-1.f, d2=lvl-2.f, d3=lvl-3.f;
      float e0=-0.5f*d0*d0, e1=-0.5f*d1*d1, e2=-0.5f*d2*d2, e3=-0.5f*d3*d3;
      float m = fmaxf(fmaxf(e0,e1),fmaxf(e2,e3));
      float x0=expf(e0-m), x1=expf(e1-m), x2=expf(e2-m), x3=expf(e3-m);
      float inv = 1.f/(x0+x1+x2+x3);
      xyb[(size_t)q*128+gp] = make_float2(sx,sy);
      lwb[(size_t)q*128+gp] = make_float4(x0*inv, x1*inv, x2*inv, x3*inv);
    }
  }
}

// ---------- MFMA helpers ----------
DI f32x4 mfma16(short8v a, short8v b, f32x4 c){
  return __builtin_amdgcn_mfma_f32_16x16x32_bf16(a, b, c, 0, 0, 0);
}

// swizzle for [128][32]-short tiles: chunk c (16B) XOR row bits -> bank-balanced b128 reads
DI int swz32(int c, int r){ return c ^ (r&3) ^ ((r>>2)&3); }

// stage a 128x32 bf16 tile into linear LDS via global_load_lds, source pre-swizzled.
DI void stageG32(const unsigned short* __restrict__ g, size_t row0, size_t ldk,
                 size_t k0, unsigned short* lds, int tid){
  int wv = tid>>6;
  #pragma unroll
  for(int i=0;i<2;i++){
    int e = i*256 + tid;          // 16B-chunk index 0..511
    int r = e>>2, c = e&3;
    int cs = swz32(c, r);
    const unsigned short* gp = g + (row0 + (size_t)r)*ldk + k0 + (size_t)cs*8;
    unsigned short* lp = lds + (size_t)(i*256 + wv*64)*8;   // wave-uniform base
    __builtin_amdgcn_global_load_lds((gp1_t)(const void*)gp, (lp3_t)(void*)lp, 16, 0, 0);
  }
}

// read one A/B fragment (row, k-chunk q4) from swizzled [128][32] tile
DI short8v frag32(const unsigned short* lds, int row, int q4){
  return *(const short8v*)(lds + (size_t)row*32 + (size_t)swz32(q4, row)*8);
}

// one BK=32 step: 4 A-frags, 4 B-frags, 16 MFMA
DI void mma32(const unsigned short* lsA, const unsigned short* lsB,
              int wm, int wn, int lane, f32x4 acc[4][4]){
  int r15 = lane&15, q4 = lane>>4;
  short8v a[4], b[4];
  #pragma unroll
  for(int i=0;i<4;i++){
    a[i] = frag32(lsA, wm*64 + i*16 + r15, q4);
    b[i] = frag32(lsB, wn*64 + i*16 + r15, q4);
  }
  #pragma unroll
  for(int mi=0;mi<4;mi++)
    #pragma unroll
    for(int ni=0;ni<4;ni++)
      acc[mi][ni] = mfma16(a[mi], b[ni], acc[mi][ni]);
}

// XCD-affinity remap: consecutive logical blocks land on one XCD (nwg % 8 == 0).
DI int xcd_remap(int bid, int nwg){
  return ((bid & 7) * (nwg >> 3)) + (bid >> 3);
}

// ---------- K2: params GEMM via MFMA: par = qfb @ wpgT^T + b_pg ----------
// 2-phase pipelined dbuf BK=32 (32 KB LDS) -> 4 blocks/CU; LDS-staged coalesced epilogue.
__global__ __launch_bounds__(256, 4) void k_pgemm_mfma(const unsigned short* __restrict__ qfb,
    const unsigned short* __restrict__ wpgT, const float* __restrict__ b_pg,
    unsigned short* __restrict__ par, int qbase, int qlim, int mtiles){
  __shared__ unsigned short pool[16384];     // 32 KB
  int bid = xcd_remap(blockIdx.x, gridDim.x);
  int mt = bid % mtiles, nt = bid / mtiles;
  size_t m0 = (size_t)mt*128, n0 = (size_t)nt*128;
  int tid = threadIdx.x, lane = tid&63, wv = tid>>6;
  int wm = wv>>1, wn = wv&1;
  int r15 = lane&15, q4 = lane>>4;
  f32x4 acc[4][4] = {};
  stageG32(qfb,  qbase+m0, 256, 0, pool, tid);
  stageG32(wpgT, n0,       256, 0, pool + 8192, tid);
  __syncthreads();
  #pragma unroll
  for(int t=0; t<8; t++){
    int co = (t&1)*4096;
    if(t<7){
      int no = ((t&1)^1)*4096;
      stageG32(qfb,  qbase+m0, 256, (size_t)(t+1)*32, pool + no, tid);
      stageG32(wpgT, n0,       256, (size_t)(t+1)*32, pool + 8192 + no, tid);
    }
    mma32(pool + co, pool + 8192 + co, wm, wn, lane, acc);
    __syncthreads();
  }
  // epilogue: stage bf16 result in LDS [128][72], store full 128B rows, two col-halves
  unsigned short* es = pool;
  #pragma unroll
  for(int h=0; h<2; ++h){
    if(h) __syncthreads();
    if(wn == h){
      #pragma unroll
      for(int ni=0; ni<4; ni++){
        float bias = b_pg[(int)n0 + wn*64 + ni*16 + r15];
        #pragma unroll
        for(int mi=0; mi<4; mi++)
          #pragma unroll
          for(int j=0; j<4; j++){
            int row = wm*64 + mi*16 + q4*4 + j;
            es[row*72 + ni*16 + r15] = f2bf(acc[mi][ni][j] + bias);
          }
      }
    }
    __syncthreads();
    #pragma unroll
    for(int i=0;i<4;i++){
      int e = i*256 + tid;              // 1024 chunks of 8 shorts
      int row = e>>3, c8 = (e&7)*8;
      int rl = (int)m0 + row;
      if(qbase + rl < qlim){
        uint4 v = *(const uint4*)(es + row*72 + c8);
        *(uint4*)&par[(size_t)rl*GTOT + n0 + h*64 + c8] = v;
      }
    }
  }
}

// ---------- K4: final GEMM via MFMA, K-split x kspl -> f32 partials ----------
// 2-phase pipelined dbuf BK=32; nt innermost so A-slice-sharing blocks are XCD-adjacent.
__global__ __launch_bounds__(256, 4) void k_fgemm_mfma(const unsigned short* __restrict__ Ag,
    const unsigned short* __restrict__ woutT, float* __restrict__ part,
    int qbase, int qlim, int mtiles, int kspl){
  __shared__ unsigned short pool[16384];
  int bid = xcd_remap(blockIdx.x, gridDim.x);
  int nt = bid & 1;
  int r2 = bid >> 1;
  int mt = r2 % mtiles, ks = r2 / mtiles;
  size_t m0 = (size_t)mt*128, n0 = (size_t)nt*128;
  int tid = threadIdx.x, lane = tid&63, wv = tid>>6;
  int wm = wv>>1, wn = wv&1;
  f32x4 acc[4][4] = {};
  int klen = GTOT / kspl;
  size_t kbase = (size_t)ks*klen;
  int NT = klen >> 5;
  stageG32(Ag,    m0, GTOT, kbase, pool, tid);
  stageG32(woutT, n0, GTOT, kbase, pool + 8192, tid);
  __syncthreads();
  for(int t=0; t<NT; t++){
    int co = (t&1)*4096;
    if(t+1<NT){
      int no = ((t&1)^1)*4096;
      stageG32(Ag,    m0, GTOT, kbase + (size_t)(t+1)*32, pool + no, tid);
      stageG32(woutT, n0, GTOT, kbase + (size_t)(t+1)*32, pool + 8192 + no, tid);
    }
    mma32(pool + co, pool + 8192 + co, wm, wn, lane, acc);
    __syncthreads();
  }
  float* pp = part + (size_t)ks*NQ*256;
  int r15 = lane&15, q4 = lane>>4;
  #pragma unroll
  for(int mi=0; mi<4; mi++){
    #pragma unroll
    for(int j=0; j<4; j++){
      int rl = (int)m0 + wm*64 + mi*16 + q4*4 + j;
      int q = qbase + rl;
      if(q < qlim){
        #pragma unroll
        for(int ni=0; ni<4; ni++){
          int col = (int)n0 + wn*64 + ni*16 + r15;
          pp[(size_t)q*256 + col] = acc[mi][ni][j];
        }
      }
    }
  }
}

// ---------- K3: sampling + M/S mixing via MFMA + two group-LN+relu -> out2 bf16 ----------
// NOTE: out2 may alias par — each block reads its full par slice into registers
// before any out2 store (same (lq,g) range, disjoint across blocks).
__global__ __launch_bounds__(256) void k_mix(const unsigned short* __restrict__ featT,
    const float2* __restrict__ xyb, const float4* __restrict__ lwb,
    const unsigned short* __restrict__ par, unsigned short* __restrict__ out2,
    int qbase){
  __shared__ __align__(16) char poolA[23040];
  __shared__ __align__(16) unsigned short Ss[128*40];   // S natural [o][p], pad 40
  __shared__ float red[8];
  float* offW = (float*)poolA;
  unsigned short* xs  = (unsigned short*)(poolA + 4096);
  unsigned short* Ms  = (unsigned short*)(poolA + 4096 + 4608);
  unsigned short* o1t = (unsigned short*)(poolA + 4096 + 4608 + 9216);
  unsigned short* o2s = (unsigned short*)poolA;

  int lq = blockIdx.x >> 2, g = blockIdx.x & 3;
  int q = qbase + lq;
  int b = q / NN;
  int bg = b*4 + g;
  int tid = threadIdx.x;
  int lane = tid & 63, wv = tid >> 6;

  const int HH[4] = {100,50,25,13};
  const int WW[4] = {160,80,40,20};
  const float IS[4] = {0.125f, 0.0625f, 0.03125f, 0.015625f};
  const int LO[4] = {0, 16384000, 20480000, 21504000};

  const unsigned short* pb = par + (size_t)lq*GTOT + (size_t)g*8192;
  uint4 mraw0 = *(const uint4*)(pb + tid*8);
  uint4 mraw1 = *(const uint4*)(pb + 2048 + tid*8);
  uint4 sraw0 = *(const uint4*)(pb + 4096 + tid*8);
  uint4 sraw1 = *(const uint4*)(pb + 6144 + tid*8);

  if(tid < 128){
    int p = tid >> 2, l = tid & 3;
    int pi = q*128 + g*32 + p;
    float2 xy = xyb[pi];
    float lw4 = ((const float*)lwb)[(size_t)pi*4 + l];
    int H = HH[l], W = WW[l];
    float px = xy.x*IS[l] - 0.5f;
    float py = xy.y*IS[l] - 0.5f;
    float xf = floorf(px), yf = floorf(py);
    float wx = px - xf, wy = py - yf;
    int x0 = (int)xf, y0 = (int)yf;
    int x1 = x0 + 1, y1 = y0 + 1;
    bool vx0 = (x0>=0)&&(x0<W), vx1 = (x1>=0)&&(x1<W);
    bool vy0 = (y0>=0)&&(y0<H), vy1 = (y1>=0)&&(y1<H);
    int x0c = min(max(x0,0),W-1), x1c = min(max(x1,0),W-1);
    int y0c = min(max(y0,0),H-1), y1c = min(max(y1,0),H-1);
    int base = LO[l] + bg*H*W*64;
    float* e = offW + tid*8;
    e[0] = __int_as_float(base + (y0c*W + x0c)*64);
    e[1] = __int_as_float(base + (y0c*W + x1c)*64);
    e[2] = __int_as_float(base + (y1c*W + x0c)*64);
    e[3] = __int_as_float(base + (y1c*W + x1c)*64);
    e[4] = (1.f-wx)*(1.f-wy)*lw4*(float)(vx0&&vy0);
    e[5] = wx*(1.f-wy)*lw4*(float)(vx1&&vy0);
    e[6] = (1.f-wx)*wy*lw4*(float)(vx0&&vy1);
    e[7] = wx*wy*lw4*(float)(vx1&&vy1);
  }

  {
    int idx0 = tid*8;
    int c0 = idx0>>6, d0 = idx0&63;
    *(uint4*)(Ms + c0*72 + d0) = mraw0;
    int idx1 = 2048 + tid*8;
    int c1 = idx1>>6, d1 = idx1&63;
    *(uint4*)(Ms + c1*72 + d1) = mraw1;
    int o0 = idx0>>5, p0 = idx0&31;
    *(uint4*)(Ss + o0*40 + p0) = sraw0;
    int o1_ = idx1>>5, p1 = idx1&31;
    *(uint4*)(Ss + o1_*40 + p1) = sraw1;
  }
  __syncthreads();

  // Phase A: paired-channel gather. half-wave per p, lane cp = channel pair.
  {
    int half = lane >> 5, cp = lane & 31;
    const unsigned short* fb_ = featT + cp*2;
    #pragma unroll
    for(int i=0;i<4;i++){
      int p = wv*8 + i*2 + half;
      const float* e = offW + p*32;
      float aLo = 0.f, aHi = 0.f;
      #pragma unroll
      for(int l=0;l<4;l++){
        float4 ea = *(const float4*)(e + l*8);
        float4 eb = *(const float4*)(e + l*8 + 4);
        unsigned u00 = *(const unsigned*)(fb_ + __float_as_int(ea.x));
        unsigned u01 = *(const unsigned*)(fb_ + __float_as_int(ea.y));
        unsigned u10 = *(const unsigned*)(fb_ + __float_as_int(ea.z));
        unsigned u11 = *(const unsigned*)(fb_ + __float_as_int(ea.w));
        aLo += eb.x*__uint_as_float(u00<<16); aHi += eb.x*__uint_as_float(u00&0xffff0000u);
        aLo += eb.y*__uint_as_float(u01<<16); aHi += eb.y*__uint_as_float(u01&0xffff0000u);
        aLo += eb.z*__uint_as_float(u10<<16); aHi += eb.z*__uint_as_float(u10&0xffff0000u);
        aLo += eb.w*__uint_as_float(u11<<16); aHi += eb.w*__uint_as_float(u11&0xffff0000u);
      }
      unsigned lo = f2bf(aLo), hi = f2bf(aHi);
      *(unsigned*)(xs + p*72 + cp*2) = lo | (hi<<16);
    }
  }
  __syncthreads();

  int r = lane & 15, q4 = lane >> 4;

  // Phase B: out1 = x(32x64) @ M(64x64)
  {
    short8v af00 = *(const short8v*)(xs + r*72 + q4*8);
    short8v af01 = *(const short8v*)(xs + r*72 + 32 + q4*8);
    short8v af10 = *(const short8v*)(xs + (16+r)*72 + q4*8);
    short8v af11 = *(const short8v*)(xs + (16+r)*72 + 32 + q4*8);
    short8v bm0, bm1;
    #pragma unroll
    for(int j=0;j<8;j++){
      bm0[j] = (short)Ms[(8*q4+j)*72 + wv*16 + r];
      bm1[j] = (short)Ms[(32+8*q4+j)*72 + wv*16 + r];
    }
    f32x4 a0 = {}, a1 = {};
    a0 = mfma16(af00, bm0, a0); a0 = mfma16(af01, bm1, a0);
    a1 = mfma16(af10, bm0, a1); a1 = mfma16(af11, bm1, a1);

    float s = 0.f, s2 = 0.f;
    #pragma unroll
    for(int v=0;v<4;v++){ s += a0[v]+a1[v]; s2 += a0[v]*a0[v] + a1[v]*a1[v]; }
    bred256(s, s2, red, tid);
    float mean = s*(1.f/2048.f);
    float var = s2*(1.f/2048.f) - mean*mean;
    float rs = rsqrtf(var + LN_EPS);
    #pragma unroll
    for(int v=0;v<4;v++){
      float f0 = (a0[v]-mean)*rs; f0 = f0>0.f ? f0 : 0.f;
      float f1 = (a1[v]-mean)*rs; f1 = f1>0.f ? f1 : 0.f;
      o1t[(wv*16+r)*40 + 4*q4 + v] = f2bf(f0);
      o1t[(wv*16+r)*40 + 16 + 4*q4 + v] = f2bf(f1);
    }
  }
  __syncthreads();

  // Phase C: out2 = S(128x32) @ out1(32x64)
  {
    short8v sa0 = *(const short8v*)(Ss + ((wv*2+0)*16 + r)*40 + q4*8);
    short8v sa1 = *(const short8v*)(Ss + ((wv*2+1)*16 + r)*40 + q4*8);
    short8v ov0 = *(const short8v*)(o1t + (r)*40 + q4*8);
    short8v ov1 = *(const short8v*)(o1t + (16+r)*40 + q4*8);
    short8v ov2 = *(const short8v*)(o1t + (32+r)*40 + q4*8);
    short8v ov3 = *(const short8v*)(o1t + (48+r)*40 + q4*8);
    f32x4 c2[2][4] = {};
    c2[0][0] = mfma16(sa0, ov0, c2[0][0]); c2[0][1] = mfma16(sa0, ov1, c2[0][1]);
    c2[0][2] = mfma16(sa0, ov2, c2[0][2]); c2[0][3] = mfma16(sa0, ov3, c2[0][3]);
    c2[1][0] = mfma16(sa1, ov0, c2[1][0]); c2[1][1] = mfma16(sa1, ov1, c2[1][1]);
    c2[1][2] = mfma16(sa1, ov2, c2[1][2]); c2[1][3] = mfma16(sa1, ov3, c2[1][3]);

    float s = 0.f, s2 = 0.f;
    #pragma unroll
    for(int m=0;m<2;m++)
      #pragma unroll
      for(int ni=0;ni<4;ni++)
        #pragma unroll
        for(int v=0;v<4;v++){ float x = c2[m][ni][v]; s += x; s2 += x*x; }
    bred256(s, s2, red, tid);
    float mean = s*(1.f/8192.f);
    float var = s2*(1.f/8192.f) - mean*mean;
    float rs = rsqrtf(var + LN_EPS);
    #pragma unroll
    for(int m=0;m<2;m++)
      #pragma unroll
      for(int ni=0;ni<4;ni++)
        #pragma unroll
        for(int v=0;v<4;v++){
          float x = (c2[m][ni][v]-mean)*rs; x = x>0.f ? x : 0.f;
          int o = (wv*2+m)*16 + 4*q4 + v;
          int d = ni*16 + r;
          o2s[o*72 + d] = f2bf(x);
        }
  }
  __syncthreads();

  unsigned short* og = out2 + (size_t)lq*GTOT + (size_t)g*8192;
  #pragma unroll
  for(int i=0;i<32;i++){
    int row = wv*32 + i;
    og[row*64 + lane] = o2s[row*72 + lane];
  }
}

// ---------- K5: K-split reduce + bias + residual + LayerNorm ----------
__global__ __launch_bounds__(256) void k_ln(const float* __restrict__ part,
    const float* __restrict__ qf, const float* __restrict__ b_out,
    const float* __restrict__ ln_g, const float* __restrict__ ln_b,
    float* __restrict__ out, int kspl){
  __shared__ float red[8];
  int q = blockIdx.x, j = threadIdx.x;
  float s = qf[(size_t)q*256 + j] + b_out[j];
  for(int ks=0; ks<kspl; ks++) s += part[((size_t)ks*NQ + q)*256 + j];
  float a = s, a2 = s*s;
  bred256(a, a2, red, j);
  float mean = a*(1.f/256.f);
  float var = a2*(1.f/256.f) - mean*mean;
  float rs = rsqrtf(var + LN_EPS);
  out[(size_t)q*256 + j] = (s-mean)*rs*ln_g[j] + ln_b[j];
}

// ---------- launch ----------
extern "C" void kernel_launch(void* const* d_in, const int* in_sizes, int n_in,
                              void* d_out, int out_size, void* d_ws, size_t ws_size,
                              hipStream_t stream) {
  const float* feat0 = (const float*)d_in[0];
  const float* feat1 = (const float*)d_in[1];
  const float* feat2 = (const float*)d_in[2];
  const float* feat3 = (const float*)d_in[3];
  const float* qf    = (const float*)d_in[4];
  const float* xyzr  = (const float*)d_in[5];
  const float* w_off = (const float*)d_in[6];
  const float* b_off = (const float*)d_in[7];
  const float* w_pg  = (const float*)d_in[8];
  const float* b_pg  = (const float*)d_in[9];
  const float* w_out = (const float*)d_in[10];
  const float* b_out = (const float*)d_in[11];
  const float* ln_g  = (const float*)d_in[12];
  const float* ln_b  = (const float*)d_in[13];

  // candidate configs: (K-split, chunk count) in preference order
  const int cand_ksp[5] = {32,16,16,16,16};
  const int cand_nc [5] = { 1, 1, 2, 4, 8};
  int KSP=0, NC=0, qcount=0, qpad=0;
  size_t oFEAT=0,oXY=0,oLW=0,oPART=0,oQFB=0,oWPGT=0,oWOUT=0,oPAR=0;
  for(int ci=0; ci<5; ci++){
    size_t o = 0;
    auto al = [&](size_t bytes){ size_t r = o; o = (o + bytes + 255) & ~255ull; return r; };
    size_t tFEAT = al(43540480ull);
    size_t tXY   = al((size_t)NQ*128*8);
    size_t tLW   = al((size_t)NQ*128*16);
    size_t tPART = al((size_t)cand_ksp[ci]*NQ*256*4);
    size_t tQFB  = al((size_t)2048*256*2);
    size_t tWPGT = al((size_t)GTOT*256*2);
    size_t tWOUT = al((size_t)256*GTOT*2);
    int qc = NQ / cand_nc[ci];
    int qp = (qc + 127) & ~127;
    size_t tPAR = al((size_t)qp*GTOT*2);
    if(o <= ws_size){
      KSP=cand_ksp[ci]; NC=cand_nc[ci]; qcount=qc; qpad=qp;
      oFEAT=tFEAT; oXY=tXY; oLW=tLW; oPART=tPART; oQFB=tQFB; oWPGT=tWPGT; oWOUT=tWOUT; oPAR=tPAR;
      break;
    }
  }
  if(NC == 0) return;

  char* ws = (char*)d_ws;
  unsigned short* featT = (unsigned short*)(ws + oFEAT);
  float2* xyb = (float2*)(ws + oXY);
  float4* lwb = (float4*)(ws + oLW);
  float* part = (float*)(ws + oPART);
  unsigned short* qfb  = (unsigned short*)(ws + oQFB);
  unsigned short* wpgT = (unsigned short*)(ws + oWPGT);
  unsigned short* woutT= (unsigned short*)(ws + oWOUT);
  unsigned short* par  = (unsigned short*)(ws + oPAR);
  unsigned short* o2   = par;   // aliased

  k_prep<<<7610, 256, 0, stream>>>(feat0, feat1, feat2, feat3, qf, xyzr,
      w_off, b_off, w_pg, w_out, featT, xyb, lwb, qfb, wpgT, woutT);

  int mtiles = qpad / 128;
  for (int c = 0; c < NC; ++c) {
    int qbase = c * qcount;
    int qlim  = qbase + qcount;
    k_pgemm_mfma<<<mtiles*256, 256, 0, stream>>>(qfb, wpgT, b_pg, par, qbase, qlim, mtiles);
    k_mix<<<qcount*4, 256, 0, stream>>>(featT, xyb, lwb, par, o2, qbase);
    k_fgemm_mfma<<<mtiles*2*KSP, 256, 0, stream>>>(o2, woutT, part, qbase, qlim, mtiles, KSP);
  }
  k_ln<<<NQ, 256, 0, stream>>>(part, qf, b_out, ln_g, ln_b, (float*)d_out, KSP);
}

// Round 11
// 296.841 us; speedup vs baseline: 1.3370x; 1.0812x over previous
//
#include <hip/hip_runtime.h>
#include <hip/hip_bf16.h>
#include <cstdint>
#include <cstddef>

#define DI __device__ __forceinline__

// ---------- constants ----------
#define NN 500
#define NQ 2000           // B*N
#define GTOT 32768        // G*TOTAL
#define LN_EPS 1e-5f

typedef __attribute__((ext_vector_type(8))) short short8v;
typedef __attribute__((ext_vector_type(4))) float f32x4;
typedef const __attribute__((address_space(1))) void* gp1_t;
typedef __attribute__((address_space(3))) void* lp3_t;

DI unsigned short f2bf(float f){
  unsigned u = __float_as_uint(f);
  return (unsigned short)((u + 0x7fffu + ((u>>16)&1u)) >> 16);
}
DI float bf2f(unsigned short s){ return __uint_as_float(((unsigned)s)<<16); }

DI ushort4 cvt4(float4 a){
  ushort4 r; r.x=f2bf(a.x); r.y=f2bf(a.y); r.z=f2bf(a.z); r.w=f2bf(a.w); return r;
}

// block-wide (256 thr = 4 waves) sum of s, s2
DI void bred256(float& s, float& s2, float* red, int tid){
  #pragma unroll
  for(int off=32; off; off>>=1){
    s  += __shfl_xor(s,  off, 64);
    s2 += __shfl_xor(s2, off, 64);
  }
  int w = tid>>6;
  if((tid&63)==0){ red[w*2]=s; red[w*2+1]=s2; }
  __syncthreads();
  s  = red[0]+red[2]+red[4]+red[6];
  s2 = red[1]+red[3]+red[5]+red[7];
  __syncthreads();
}

// ---------- K-prep: fused prepasses (heavy-first block order, 256 thr) ----------
// [0,250)       offset GEMM + sample coords + level softmax  (heaviest, first)
// [250,3258)    feature transpose (B,C,H,W) f32 -> (B*G,H,W,64) bf16
// [3258,3514)   qf f32 -> bf16 [2048][256] (pad rows zeroed)
// [3514,5562)   w_pg  [256][32768] -> wpgT  [32768][256] bf16
// [5562,7610)   w_out [32768][256] -> woutT [256][32768] bf16
__global__ __launch_bounds__(256) void k_prep(
    const float* __restrict__ f0, const float* __restrict__ f1,
    const float* __restrict__ f2, const float* __restrict__ f3,
    const float* __restrict__ qf, const float* __restrict__ xyzr,
    const float* __restrict__ w_off, const float* __restrict__ b_off,
    const float* __restrict__ w_pg, const float* __restrict__ w_out,
    unsigned short* __restrict__ featT, float2* __restrict__ xyb,
    float4* __restrict__ lwb, unsigned short* __restrict__ qfb,
    unsigned short* __restrict__ wpgT, unsigned short* __restrict__ woutT){
  __shared__ __align__(16) char P[20992];     // 20.5 KB max branch -> 7 blocks/CU
  int bid = blockIdx.x, tid = threadIdx.x;

  if(bid < 250){
    // ---- offset GEMM + coords + softmax (8 queries / block) ----
    float (*qs)[256] = (float(*)[256])P;
    float (*os)[384] = (float(*)[384])(P + 8192);
    int q0 = bid*8;
    for(int idx=tid; idx<2048; idx+=256){
      int qq = idx>>8, k = idx&255;
      qs[qq][k] = qf[(size_t)(q0+qq)*256 + k];
    }
    __syncthreads();
    #pragma unroll
    for(int jj=0; jj<2; jj++){
      int j = tid + jj*256;
      if(j < 384){
        float acc[8];
        #pragma unroll
        for(int i=0;i<8;i++) acc[i]=0.f;
        for(int k=0;k<256;k++){
          float w = w_off[(size_t)k*384 + j];
          #pragma unroll
          for(int qq=0;qq<8;qq++) acc[qq] += qs[qq][k]*w;
        }
        float bb = b_off[j];
        #pragma unroll
        for(int qq=0;qq<8;qq++) os[qq][j] = acc[qq] + bb;
      }
    }
    __syncthreads();
    for(int idx=tid; idx<1024; idx+=256){
      int qq = idx>>7, gp = idx&127;
      int q = q0+qq;
      float4 xr = *(const float4*)&xyzr[(size_t)q*4];
      float rw = exp2f(xr.z - 0.5f*xr.w);
      float rh = exp2f(xr.z + 0.5f*xr.w);
      float sx = xr.x + os[qq][gp*3+0]*rw;
      float sy = xr.y + os[qq][gp*3+1]*rh;
      float lvl = xr.z + os[qq][gp*3+2] - 3.0f;
      float d0=lvl, d1=lvl-1.f, d2=lvl-2.f, d3=lvl-3.f;
      float e0=-0.5f*d0*d0, e1=-0.5f*d1*d1, e2=-0.5f*d2*d2, e3=-0.5f*d3*d3;
      float m = fmaxf(fmaxf(e0,e1),fmaxf(e2,e3));
      float x0=expf(e0-m), x1=expf(e1-m), x2=expf(e2-m), x3=expf(e3-m);
      float inv = 1.f/(x0+x1+x2+x3);
      xyb[(size_t)q*128+gp] = make_float2(sx,sy);
      lwb[(size_t)q*128+gp] = make_float4(x0*inv, x1*inv, x2*inv, x3*inv);
    }
  } else if(bid < 3258){
    // ---- feature transpose: f32x4 loads, bf16 LDS tile, ushort4 stores ----
    const float* src; unsigned short* dst; int H, W, lb;
    int fb = bid - 250;
    if(fb < 1600){ src=f0; dst=featT;            H=100; W=160; lb=fb; }
    else if(fb < 2400){ src=f1; dst=featT+16384000; H=50; W=80; lb=fb-1600; }
    else if(fb < 2800){ src=f2; dst=featT+20480000; H=25; W=40; lb=fb-2400; }
    else { src=f3; dst=featT+21504000; H=13; W=20; lb=fb-2800; }
    unsigned short* tile = (unsigned short*)P;   // [64][164] bf16
    int bg = lb / H, h = lb % H;
    int b = bg >> 2, g = bg & 3;
    const float* s = src + (((size_t)(b*256 + g*64))*H + h)*(size_t)W;
    int W4 = W >> 2;
    for(int idx=tid; idx<64*W4; idx+=256){
      int c = idx / W4, w4 = idx - c*W4;
      float4 v = *(const float4*)(s + (size_t)c*H*W + w4*4);
      *(ushort4*)(tile + c*164 + w4*4) = cvt4(v);
    }
    __syncthreads();
    unsigned short* d = dst + ((size_t)bg*H + h)*(size_t)W*64;
    for(int idx=tid; idx<16*W; idx+=256){
      int w = idx >> 4, c4 = idx & 15;
      ushort4 v;
      v.x = tile[(c4*4+0)*164 + w];
      v.y = tile[(c4*4+1)*164 + w];
      v.z = tile[(c4*4+2)*164 + w];
      v.w = tile[(c4*4+3)*164 + w];
      *(ushort4*)(d + w*64 + c4*4) = v;
    }
  } else if(bid < 3514){
    // ---- qf -> bf16 padded ----
    int idx = (bid-3258)*256 + tid;
    size_t base = (size_t)idx*8;
    int row = idx >> 5;
    ushort4 lo, hi;
    if(row < NQ){
      float4 a = *(const float4*)(qf + base);
      float4 b = *(const float4*)(qf + base + 4);
      lo = cvt4(a); hi = cvt4(b);
    } else {
      lo.x=lo.y=lo.z=lo.w=0; hi.x=hi.y=hi.z=hi.w=0;
    }
    *(ushort4*)(qfb + base) = lo;
    *(ushort4*)(qfb + base + 4) = hi;
  } else {
    // ---- transpose-convert weight matrices: f32x4 loads, bf16 tile, ushort4 stores ----
    const float* src; unsigned short* dst; int R, C, lb;
    if(bid < 5562){ src=w_pg;  dst=wpgT;  R=256;  C=GTOT; lb=bid-3514; }
    else          { src=w_out; dst=woutT; R=GTOT; C=256;  lb=bid-5562; }
    unsigned short* tile = (unsigned short*)P;   // [64][68] bf16
    int ctiles = C >> 6;
    int rt = lb / ctiles, ct = lb % ctiles;
    int r0 = rt<<6, c0 = ct<<6;
    #pragma unroll
    for(int i=0;i<4;i++){
      int idx = tid + i*256;          // 1024 float4 chunks
      int r = idx >> 4, c4 = idx & 15;
      float4 v = *(const float4*)(src + (size_t)(r0+r)*C + c0 + c4*4);
      *(ushort4*)(tile + r*68 + c4*4) = cvt4(v);
    }
    __syncthreads();
    #pragma unroll
    for(int i=0;i<4;i++){
      int idx = tid + i*256;          // 1024 ushort4 chunks
      int cc = idx >> 4, r4 = idx & 15;
      ushort4 v;
      v.x = tile[(r4*4+0)*68 + cc];
      v.y = tile[(r4*4+1)*68 + cc];
      v.z = tile[(r4*4+2)*68 + cc];
      v.w = tile[(r4*4+3)*68 + cc];
      *(ushort4*)(dst + (size_t)(c0+cc)*R + r0 + r4*4) = v;
    }
  }
}

// ---------- MFMA helpers ----------
DI f32x4 mfma16(short8v a, short8v b, f32x4 c){
  return __builtin_amdgcn_mfma_f32_16x16x32_bf16(a, b, c, 0, 0, 0);
}

// swizzle for [128][32]-short tiles: chunk c (16B) XOR row bits -> bank-balanced b128 reads
DI int swz32(int c, int r){ return c ^ (r&3) ^ ((r>>2)&3); }

// stage a 128x32 bf16 tile into linear LDS via global_load_lds, source pre-swizzled.
DI void stageG32(const unsigned short* __restrict__ g, size_t row0, size_t ldk,
                 size_t k0, unsigned short* lds, int tid){
  int wv = tid>>6;
  #pragma unroll
  for(int i=0;i<2;i++){
    int e = i*256 + tid;          // 16B-chunk index 0..511
    int r = e>>2, c = e&3;
    int cs = swz32(c, r);
    const unsigned short* gp = g + (row0 + (size_t)r)*ldk + k0 + (size_t)cs*8;
    unsigned short* lp = lds + (size_t)(i*256 + wv*64)*8;   // wave-uniform base
    __builtin_amdgcn_global_load_lds((gp1_t)(const void*)gp, (lp3_t)(void*)lp, 16, 0, 0);
  }
}

// read one A/B fragment (row, k-chunk q4) from swizzled [128][32] tile
DI short8v frag32(const unsigned short* lds, int row, int q4){
  return *(const short8v*)(lds + (size_t)row*32 + (size_t)swz32(q4, row)*8);
}

// one BK=32 step: 4 A-frags, 4 B-frags, 16 MFMA
DI void mma32(const unsigned short* lsA, const unsigned short* lsB,
              int wm, int wn, int lane, f32x4 acc[4][4]){
  int r15 = lane&15, q4 = lane>>4;
  short8v a[4], b[4];
  #pragma unroll
  for(int i=0;i<4;i++){
    a[i] = frag32(lsA, wm*64 + i*16 + r15, q4);
    b[i] = frag32(lsB, wn*64 + i*16 + r15, q4);
  }
  #pragma unroll
  for(int mi=0;mi<4;mi++)
    #pragma unroll
    for(int ni=0;ni<4;ni++)
      acc[mi][ni] = mfma16(a[mi], b[ni], acc[mi][ni]);
}

// XCD-affinity remap: consecutive logical blocks land on one XCD (nwg % 8 == 0).
DI int xcd_remap(int bid, int nwg){
  return ((bid & 7) * (nwg >> 3)) + (bid >> 3);
}

// ---------- K2: params GEMM via MFMA: par = qfb @ wpgT^T + b_pg ----------
// 2-phase pipelined dbuf BK=32 (32 KB LDS) -> 4 blocks/CU; LDS-staged coalesced epilogue.
__global__ __launch_bounds__(256, 4) void k_pgemm_mfma(const unsigned short* __restrict__ qfb,
    const unsigned short* __restrict__ wpgT, const float* __restrict__ b_pg,
    unsigned short* __restrict__ par, int qbase, int qlim, int mtiles){
  __shared__ unsigned short pool[16384];     // 32 KB
  int bid = xcd_remap(blockIdx.x, gridDim.x);
  int mt = bid % mtiles, nt = bid / mtiles;
  size_t m0 = (size_t)mt*128, n0 = (size_t)nt*128;
  int tid = threadIdx.x, lane = tid&63, wv = tid>>6;
  int wm = wv>>1, wn = wv&1;
  int r15 = lane&15, q4 = lane>>4;
  f32x4 acc[4][4] = {};
  stageG32(qfb,  qbase+m0, 256, 0, pool, tid);
  stageG32(wpgT, n0,       256, 0, pool + 8192, tid);
  __syncthreads();
  #pragma unroll
  for(int t=0; t<8; t++){
    int co = (t&1)*4096;
    if(t<7){
      int no = ((t&1)^1)*4096;
      stageG32(qfb,  qbase+m0, 256, (size_t)(t+1)*32, pool + no, tid);
      stageG32(wpgT, n0,       256, (size_t)(t+1)*32, pool + 8192 + no, tid);
    }
    mma32(pool + co, pool + 8192 + co, wm, wn, lane, acc);
    __syncthreads();
  }
  // epilogue: stage bf16 result in LDS [128][72], store full 128B rows, two col-halves
  unsigned short* es = pool;
  #pragma unroll
  for(int h=0; h<2; ++h){
    if(h) __syncthreads();
    if(wn == h){
      #pragma unroll
      for(int ni=0; ni<4; ni++){
        float bias = b_pg[(int)n0 + wn*64 + ni*16 + r15];
        #pragma unroll
        for(int mi=0; mi<4; mi++)
          #pragma unroll
          for(int j=0; j<4; j++){
            int row = wm*64 + mi*16 + q4*4 + j;
            es[row*72 + ni*16 + r15] = f2bf(acc[mi][ni][j] + bias);
          }
      }
    }
    __syncthreads();
    #pragma unroll
    for(int i=0;i<4;i++){
      int e = i*256 + tid;              // 1024 chunks of 8 shorts
      int row = e>>3, c8 = (e&7)*8;
      int rl = (int)m0 + row;
      if(qbase + rl < qlim){
        uint4 v = *(const uint4*)(es + row*72 + c8);
        *(uint4*)&par[(size_t)rl*GTOT + n0 + h*64 + c8] = v;
      }
    }
  }
}

// ---------- K4: final GEMM via MFMA, K-split x kspl -> f32 partials ----------
// 2-phase pipelined dbuf BK=32; nt innermost so A-slice-sharing blocks are XCD-adjacent.
__global__ __launch_bounds__(256, 4) void k_fgemm_mfma(const unsigned short* __restrict__ Ag,
    const unsigned short* __restrict__ woutT, float* __restrict__ part,
    int qbase, int qlim, int mtiles, int kspl){
  __shared__ unsigned short pool[16384];
  int bid = xcd_remap(blockIdx.x, gridDim.x);
  int nt = bid & 1;
  int r2 = bid >> 1;
  int mt = r2 % mtiles, ks = r2 / mtiles;
  size_t m0 = (size_t)mt*128, n0 = (size_t)nt*128;
  int tid = threadIdx.x, lane = tid&63, wv = tid>>6;
  int wm = wv>>1, wn = wv&1;
  f32x4 acc[4][4] = {};
  int klen = GTOT / kspl;
  size_t kbase = (size_t)ks*klen;
  int NT = klen >> 5;
  stageG32(Ag,    m0, GTOT, kbase, pool, tid);
  stageG32(woutT, n0, GTOT, kbase, pool + 8192, tid);
  __syncthreads();
  for(int t=0; t<NT; t++){
    int co = (t&1)*4096;
    if(t+1<NT){
      int no = ((t&1)^1)*4096;
      stageG32(Ag,    m0, GTOT, kbase + (size_t)(t+1)*32, pool + no, tid);
      stageG32(woutT, n0, GTOT, kbase + (size_t)(t+1)*32, pool + 8192 + no, tid);
    }
    mma32(pool + co, pool + 8192 + co, wm, wn, lane, acc);
    __syncthreads();
  }
  float* pp = part + (size_t)ks*NQ*256;
  int r15 = lane&15, q4 = lane>>4;
  #pragma unroll
  for(int mi=0; mi<4; mi++){
    #pragma unroll
    for(int j=0; j<4; j++){
      int rl = (int)m0 + wm*64 + mi*16 + q4*4 + j;
      int q = qbase + rl;
      if(q < qlim){
        #pragma unroll
        for(int ni=0; ni<4; ni++){
          int col = (int)n0 + wn*64 + ni*16 + r15;
          pp[(size_t)q*256 + col] = acc[mi][ni][j];
        }
      }
    }
  }
}

// ---------- K3: sampling + M/S mixing via MFMA + two group-LN+relu -> out2 bf16 ----------
// NOTE: out2 may alias par — each block reads its full par slice into registers
// before any out2 store (same (lq,g) range, disjoint across blocks).
__global__ __launch_bounds__(256) void k_mix(const unsigned short* __restrict__ featT,
    const float2* __restrict__ xyb, const float4* __restrict__ lwb,
    const unsigned short* __restrict__ par, unsigned short* __restrict__ out2,
    int qbase){
  __shared__ __align__(16) char poolA[23040];
  __shared__ __align__(16) unsigned short Ss[128*40];   // S natural [o][p], pad 40
  __shared__ float red[8];
  float* offW = (float*)poolA;
  unsigned short* xs  = (unsigned short*)(poolA + 4096);
  unsigned short* Ms  = (unsigned short*)(poolA + 4096 + 4608);
  unsigned short* o1t = (unsigned short*)(poolA + 4096 + 4608 + 9216);
  unsigned short* o2s = (unsigned short*)poolA;

  int lq = blockIdx.x >> 2, g = blockIdx.x & 3;
  int q = qbase + lq;
  int b = q / NN;
  int bg = b*4 + g;
  int tid = threadIdx.x;
  int lane = tid & 63, wv = tid >> 6;

  const int HH[4] = {100,50,25,13};
  const int WW[4] = {160,80,40,20};
  const float IS[4] = {0.125f, 0.0625f, 0.03125f, 0.015625f};
  const int LO[4] = {0, 16384000, 20480000, 21504000};

  const unsigned short* pb = par + (size_t)lq*GTOT + (size_t)g*8192;
  uint4 mraw0 = *(const uint4*)(pb + tid*8);
  uint4 mraw1 = *(const uint4*)(pb + 2048 + tid*8);
  uint4 sraw0 = *(const uint4*)(pb + 4096 + tid*8);
  uint4 sraw1 = *(const uint4*)(pb + 6144 + tid*8);

  if(tid < 128){
    int p = tid >> 2, l = tid & 3;
    int pi = q*128 + g*32 + p;
    float2 xy = xyb[pi];
    float lw4 = ((const float*)lwb)[(size_t)pi*4 + l];
    int H = HH[l], W = WW[l];
    float px = xy.x*IS[l] - 0.5f;
    float py = xy.y*IS[l] - 0.5f;
    float xf = floorf(px), yf = floorf(py);
    float wx = px - xf, wy = py - yf;
    int x0 = (int)xf, y0 = (int)yf;
    int x1 = x0 + 1, y1 = y0 + 1;
    bool vx0 = (x0>=0)&&(x0<W), vx1 = (x1>=0)&&(x1<W);
    bool vy0 = (y0>=0)&&(y0<H), vy1 = (y1>=0)&&(y1<H);
    int x0c = min(max(x0,0),W-1), x1c = min(max(x1,0),W-1);
    int y0c = min(max(y0,0),H-1), y1c = min(max(y1,0),H-1);
    int base = LO[l] + bg*H*W*64;
    float* e = offW + tid*8;
    e[0] = __int_as_float(base + (y0c*W + x0c)*64);
    e[1] = __int_as_float(base + (y0c*W + x1c)*64);
    e[2] = __int_as_float(base + (y1c*W + x0c)*64);
    e[3] = __int_as_float(base + (y1c*W + x1c)*64);
    e[4] = (1.f-wx)*(1.f-wy)*lw4*(float)(vx0&&vy0);
    e[5] = wx*(1.f-wy)*lw4*(float)(vx1&&vy0);
    e[6] = (1.f-wx)*wy*lw4*(float)(vx0&&vy1);
    e[7] = wx*wy*lw4*(float)(vx1&&vy1);
  }

  {
    int idx0 = tid*8;
    int c0 = idx0>>6, d0 = idx0&63;
    *(uint4*)(Ms + c0*72 + d0) = mraw0;
    int idx1 = 2048 + tid*8;
    int c1 = idx1>>6, d1 = idx1&63;
    *(uint4*)(Ms + c1*72 + d1) = mraw1;
    int o0 = idx0>>5, p0 = idx0&31;
    *(uint4*)(Ss + o0*40 + p0) = sraw0;
    int o1_ = idx1>>5, p1 = idx1&31;
    *(uint4*)(Ss + o1_*40 + p1) = sraw1;
  }
  __syncthreads();

  // Phase A: paired-channel gather. half-wave per p, lane cp = channel pair.
  {
    int half = lane >> 5, cp = lane & 31;
    const unsigned short* fb_ = featT + cp*2;
    #pragma unroll
    for(int i=0;i<4;i++){
      int p = wv*8 + i*2 + half;
      const float* e = offW + p*32;
      float aLo = 0.f, aHi = 0.f;
      #pragma unroll
      for(int l=0;l<4;l++){
        float4 ea = *(const float4*)(e + l*8);
        float4 eb = *(const float4*)(e + l*8 + 4);
        unsigned u00 = *(const unsigned*)(fb_ + __float_as_int(ea.x));
        unsigned u01 = *(const unsigned*)(fb_ + __float_as_int(ea.y));
        unsigned u10 = *(const unsigned*)(fb_ + __float_as_int(ea.z));
        unsigned u11 = *(const unsigned*)(fb_ + __float_as_int(ea.w));
        aLo += eb.x*__uint_as_float(u00<<16); aHi += eb.x*__uint_as_float(u00&0xffff0000u);
        aLo += eb.y*__uint_as_float(u01<<16); aHi += eb.y*__uint_as_float(u01&0xffff0000u);
        aLo += eb.z*__uint_as_float(u10<<16); aHi += eb.z*__uint_as_float(u10&0xffff0000u);
        aLo += eb.w*__uint_as_float(u11<<16); aHi += eb.w*__uint_as_float(u11&0xffff0000u);
      }
      unsigned lo = f2bf(aLo), hi = f2bf(aHi);
      *(unsigned*)(xs + p*72 + cp*2) = lo | (hi<<16);
    }
  }
  __syncthreads();

  int r = lane & 15, q4 = lane >> 4;

  // Phase B: out1 = x(32x64) @ M(64x64)
  {
    short8v af00 = *(const short8v*)(xs + r*72 + q4*8);
    short8v af01 = *(const short8v*)(xs + r*72 + 32 + q4*8);
    short8v af10 = *(const short8v*)(xs + (16+r)*72 + q4*8);
    short8v af11 = *(const short8v*)(xs + (16+r)*72 + 32 + q4*8);
    short8v bm0, bm1;
    #pragma unroll
    for(int j=0;j<8;j++){
      bm0[j] = (short)Ms[(8*q4+j)*72 + wv*16 + r];
      bm1[j] = (short)Ms[(32+8*q4+j)*72 + wv*16 + r];
    }
    f32x4 a0 = {}, a1 = {};
    a0 = mfma16(af00, bm0, a0); a0 = mfma16(af01, bm1, a0);
    a1 = mfma16(af10, bm0, a1); a1 = mfma16(af11, bm1, a1);

    float s = 0.f, s2 = 0.f;
    #pragma unroll
    for(int v=0;v<4;v++){ s += a0[v]+a1[v]; s2 += a0[v]*a0[v] + a1[v]*a1[v]; }
    bred256(s, s2, red, tid);
    float mean = s*(1.f/2048.f);
    float var = s2*(1.f/2048.f) - mean*mean;
    float rs = rsqrtf(var + LN_EPS);
    #pragma unroll
    for(int v=0;v<4;v++){
      float f0 = (a0[v]-mean)*rs; f0 = f0>0.f ? f0 : 0.f;
      float f1 = (a1[v]-mean)*rs; f1 = f1>0.f ? f1 : 0.f;
      o1t[(wv*16+r)*40 + 4*q4 + v] = f2bf(f0);
      o1t[(wv*16+r)*40 + 16 + 4*q4 + v] = f2bf(f1);
    }
  }
  __syncthreads();

  // Phase C: out2 = S(128x32) @ out1(32x64)
  {
    short8v sa0 = *(const short8v*)(Ss + ((wv*2+0)*16 + r)*40 + q4*8);
    short8v sa1 = *(const short8v*)(Ss + ((wv*2+1)*16 + r)*40 + q4*8);
    short8v ov0 = *(const short8v*)(o1t + (r)*40 + q4*8);
    short8v ov1 = *(const short8v*)(o1t + (16+r)*40 + q4*8);
    short8v ov2 = *(const short8v*)(o1t + (32+r)*40 + q4*8);
    short8v ov3 = *(const short8v*)(o1t + (48+r)*40 + q4*8);
    f32x4 c2[2][4] = {};
    c2[0][0] = mfma16(sa0, ov0, c2[0][0]); c2[0][1] = mfma16(sa0, ov1, c2[0][1]);
    c2[0][2] = mfma16(sa0, ov2, c2[0][2]); c2[0][3] = mfma16(sa0, ov3, c2[0][3]);
    c2[1][0] = mfma16(sa1, ov0, c2[1][0]); c2[1][1] = mfma16(sa1, ov1, c2[1][1]);
    c2[1][2] = mfma16(sa1, ov2, c2[1][2]); c2[1][3] = mfma16(sa1, ov3, c2[1][3]);

    float s = 0.f, s2 = 0.f;
    #pragma unroll
    for(int m=0;m<2;m++)
      #pragma unroll
      for(int ni=0;ni<4;ni++)
        #pragma unroll
        for(int v=0;v<4;v++){ float x = c2[m][ni][v]; s += x; s2 += x*x; }
    bred256(s, s2, red, tid);
    float mean = s*(1.f/8192.f);
    float var = s2*(1.f/8192.f) - mean*mean;
    float rs = rsqrtf(var + LN_EPS);
    #pragma unroll
    for(int m=0;m<2;m++)
      #pragma unroll
      for(int ni=0;ni<4;ni++)
        #pragma unroll
        for(int v=0;v<4;v++){
          float x = (c2[m][ni][v]-mean)*rs; x = x>0.f ? x : 0.f;
          int o = (wv*2+m)*16 + 4*q4 + v;
          int d = ni*16 + r;
          o2s[o*72 + d] = f2bf(x);
        }
  }
  __syncthreads();

  unsigned short* og = out2 + (size_t)lq*GTOT + (size_t)g*8192;
  #pragma unroll
  for(int i=0;i<32;i++){
    int row = wv*32 + i;
    og[row*64 + lane] = o2s[row*72 + lane];
  }
}

// ---------- K5: K-split reduce + bias + residual + LayerNorm ----------
__global__ __launch_bounds__(256) void k_ln(const float* __restrict__ part,
    const float* __restrict__ qf, const float* __restrict__ b_out,
    const float* __restrict__ ln_g, const float* __restrict__ ln_b,
    float* __restrict__ out, int kspl){
  __shared__ float red[8];
  int q = blockIdx.x, j = threadIdx.x;
  float s = qf[(size_t)q*256 + j] + b_out[j];
  for(int ks=0; ks<kspl; ks++) s += part[((size_t)ks*NQ + q)*256 + j];
  float a = s, a2 = s*s;
  bred256(a, a2, red, j);
  float mean = a*(1.f/256.f);
  float var = a2*(1.f/256.f) - mean*mean;
  float rs = rsqrtf(var + LN_EPS);
  out[(size_t)q*256 + j] = (s-mean)*rs*ln_g[j] + ln_b[j];
}

// ---------- launch ----------
extern "C" void kernel_launch(void* const* d_in, const int* in_sizes, int n_in,
                              void* d_out, int out_size, void* d_ws, size_t ws_size,
                              hipStream_t stream) {
  const float* feat0 = (const float*)d_in[0];
  const float* feat1 = (const float*)d_in[1];
  const float* feat2 = (const float*)d_in[2];
  const float* feat3 = (const float*)d_in[3];
  const float* qf    = (const float*)d_in[4];
  const float* xyzr  = (const float*)d_in[5];
  const float* w_off = (const float*)d_in[6];
  const float* b_off = (const float*)d_in[7];
  const float* w_pg  = (const float*)d_in[8];
  const float* b_pg  = (const float*)d_in[9];
  const float* w_out = (const float*)d_in[10];
  const float* b_out = (const float*)d_in[11];
  const float* ln_g  = (const float*)d_in[12];
  const float* ln_b  = (const float*)d_in[13];

  // candidate configs: (K-split, chunk count) in preference order
  const int cand_ksp[5] = {32,16,16,16,16};
  const int cand_nc [5] = { 1, 1, 2, 4, 8};
  int KSP=0, NC=0, qcount=0, qpad=0;
  size_t oFEAT=0,oXY=0,oLW=0,oPART=0,oQFB=0,oWPGT=0,oWOUT=0,oPAR=0;
  for(int ci=0; ci<5; ci++){
    size_t o = 0;
    auto al = [&](size_t bytes){ size_t r = o; o = (o + bytes + 255) & ~255ull; return r; };
    size_t tFEAT = al(43540480ull);
    size_t tXY   = al((size_t)NQ*128*8);
    size_t tLW   = al((size_t)NQ*128*16);
    size_t tPART = al((size_t)cand_ksp[ci]*NQ*256*4);
    size_t tQFB  = al((size_t)2048*256*2);
    size_t tWPGT = al((size_t)GTOT*256*2);
    size_t tWOUT = al((size_t)256*GTOT*2);
    int qc = NQ / cand_nc[ci];
    int qp = (qc + 127) & ~127;
    size_t tPAR = al((size_t)qp*GTOT*2);
    if(o <= ws_size){
      KSP=cand_ksp[ci]; NC=cand_nc[ci]; qcount=qc; qpad=qp;
      oFEAT=tFEAT; oXY=tXY; oLW=tLW; oPART=tPART; oQFB=tQFB; oWPGT=tWPGT; oWOUT=tWOUT; oPAR=tPAR;
      break;
    }
  }
  if(NC == 0) return;

  char* ws = (char*)d_ws;
  unsigned short* featT = (unsigned short*)(ws + oFEAT);
  float2* xyb = (float2*)(ws + oXY);
  float4* lwb = (float4*)(ws + oLW);
  float* part = (float*)(ws + oPART);
  unsigned short* qfb  = (unsigned short*)(ws + oQFB);
  unsigned short* wpgT = (unsigned short*)(ws + oWPGT);
  unsigned short* woutT= (unsigned short*)(ws + oWOUT);
  unsigned short* par  = (unsigned short*)(ws + oPAR);
  unsigned short* o2   = par;   // aliased

  k_prep<<<7610, 256, 0, stream>>>(feat0, feat1, feat2, feat3, qf, xyzr,
      w_off, b_off, w_pg, w_out, featT, xyb, lwb, qfb, wpgT, woutT);

  int mtiles = qpad / 128;
  for (int c = 0; c < NC; ++c) {
    int qbase = c * qcount;
    int qlim  = qbase + qcount;
    k_pgemm_mfma<<<mtiles*256, 256, 0, stream>>>(qfb, wpgT, b_pg, par, qbase, qlim, mtiles);
    k_mix<<<qcount*4, 256, 0, stream>>>(featT, xyb, lwb, par, o2, qbase);
    k_fgemm_mfma<<<mtiles*2*KSP, 256, 0, stream>>>(o2, woutT, part, qbase, qlim, mtiles, KSP);
  }
  k_ln<<<NQ, 256, 0, stream>>>(part, qf, b_out, ln_g, ln_b, (float*)d_out, KSP);
}